// Round 3
// baseline (645.057 us; speedup 1.0000x reference)
//
#include <hip/hip_runtime.h>

// ---------------- CSR build ----------------

__global__ __launch_bounds__(256) void count_kernel(const int* __restrict__ col,
                                                    int* __restrict__ cnt, int E) {
    int e = blockIdx.x * 256 + threadIdx.x;
    if (e < E) atomicAdd(&cnt[col[e]], 1);
}

// Hierarchical scan, stage 1: per-block exclusive scan + block totals.
__global__ __launch_bounds__(256) void scan_block_kernel(const int* __restrict__ cnt,
                                                         int* __restrict__ off,
                                                         int* __restrict__ bsum, int n) {
    const int gid = blockIdx.x * 256 + threadIdx.x;
    const int v = (gid < n) ? cnt[gid] : 0;
    const int lane = threadIdx.x & 63, w = threadIdx.x >> 6;
    int x = v;
#pragma unroll
    for (int d = 1; d < 64; d <<= 1) {
        int t = __shfl_up(x, d);
        if (lane >= d) x += t;
    }
    __shared__ int wt[4];
    if (lane == 63) wt[w] = x;
    __syncthreads();
    int base = 0;
#pragma unroll
    for (int i = 0; i < 3; ++i)
        if (i < w) base += wt[i];
    const int incl = base + x;
    if (gid < n) off[gid] = incl - v;
    if (threadIdx.x == 255) bsum[blockIdx.x] = incl;
}

__global__ __launch_bounds__(256) void scan_bsum_kernel(const int* __restrict__ bsum,
                                                        int* __restrict__ bbase, int nb) {
    const int tid = threadIdx.x;
    const int v = (tid < nb) ? bsum[tid] : 0;
    const int lane = tid & 63, w = tid >> 6;
    int x = v;
#pragma unroll
    for (int d = 1; d < 64; d <<= 1) {
        int t = __shfl_up(x, d);
        if (lane >= d) x += t;
    }
    __shared__ int wt[4];
    if (lane == 63) wt[w] = x;
    __syncthreads();
    int base = 0;
#pragma unroll
    for (int i = 0; i < 3; ++i)
        if (i < w) base += wt[i];
    if (tid < nb) bbase[tid] = base + x - v;
}

__global__ __launch_bounds__(256) void scan_apply_kernel(int* __restrict__ off,
                                                         const int* __restrict__ bbase,
                                                         int n, int E) {
    const int gid = blockIdx.x * 256 + threadIdx.x;
    if (gid < n) off[gid] += bbase[blockIdx.x];
    if (gid == n) off[n] = E;
}

__global__ __launch_bounds__(256) void dinv_kernel(const int* __restrict__ cnt,
                                                   float* __restrict__ dinv, int n) {
    int i = blockIdx.x * 256 + threadIdx.x;
    if (i < n) {
        int c = cnt[i];
        dinv[i] = (c > 0) ? 1.0f / sqrtf((float)c) : 0.0f;
    }
}

// src-only records: norm factorizes as dinv[src]*dinv[dst], computed in the props.
__global__ __launch_bounds__(256) void scatter_kernel(const int* __restrict__ row,
                                                      const int* __restrict__ col,
                                                      const int* __restrict__ off,
                                                      int* __restrict__ cursor,
                                                      int* __restrict__ recs, int E) {
    int e = blockIdx.x * 256 + threadIdx.x;
    if (e >= E) return;
    int pos = off[col[e]] + atomicAdd(&cursor[col[e]], 1);
    recs[pos] = row[e];
}

// ---------------- standalone prop (layer 4, 4-dim rows, 1 lane/node) ----------------

__global__ __launch_bounds__(256) void prop1_kernel(const int* __restrict__ off,
                                                    const int* __restrict__ recs,
                                                    const float* __restrict__ dinv,
                                                    const float* __restrict__ hin,
                                                    float* __restrict__ hout, int nNodes) {
    const int n = blockIdx.x * 256 + threadIdx.x;
    if (n >= nNodes) return;
    const float4* __restrict__ h4 = (const float4*)hin;
    float4 acc = make_float4(0.f, 0.f, 0.f, 0.f);
    int e = off[n];
    const int e1 = off[n + 1];
    for (; e + 4 <= e1; e += 4) {
        const int s0 = recs[e + 0], s1 = recs[e + 1], s2 = recs[e + 2], s3 = recs[e + 3];
        const float w0 = dinv[s0], w1 = dinv[s1], w2 = dinv[s2], w3 = dinv[s3];
        const float4 a = h4[s0], b = h4[s1], c = h4[s2], d = h4[s3];
        acc.x += w0 * a.x + w1 * b.x + w2 * c.x + w3 * d.x;
        acc.y += w0 * a.y + w1 * b.y + w2 * c.y + w3 * d.y;
        acc.z += w0 * a.z + w1 * b.z + w2 * c.z + w3 * d.z;
        acc.w += w0 * a.w + w1 * b.w + w2 * c.w + w3 * d.w;
    }
    for (; e < e1; ++e) {
        const int s = recs[e];
        const float ww = dinv[s];
        const float4 hv = h4[s];
        acc.x += ww * hv.x;
        acc.y += ww * hv.y;
        acc.z += ww * hv.z;
        acc.w += ww * hv.w;
    }
    const float dn = dinv[n];
    ((float4*)hout)[n] = make_float4(acc.x * dn, acc.y * dn, acc.z * dn, acc.w * dn);
}

// ---------------- fused prop + GEMM(DIN->64) accumulate ----------------
// DQ lanes per node (DIN = 4*DQ). Gather phase computes the propagated row into
// registers, optionally writes it to hout (needed when a further hop consumes it),
// stages it in LDS, then a block-local GEMM accumulates row@W into out (+ReLU last).

template <int DQ, bool WRITE_H, bool RELU>
__global__ __launch_bounds__(256) void prop_gemm64_kernel(
    const int* __restrict__ off, const int* __restrict__ recs,
    const float* __restrict__ dinv, const float* __restrict__ hin,
    float* __restrict__ hout, const float* __restrict__ W, float* __restrict__ out,
    int nNodes) {
    constexpr int DIN = DQ * 4;
    constexpr int NPB = 256 / DQ;  // nodes per block
    __shared__ __align__(16) float Ws[DIN * 64];
    __shared__ __align__(16) float hs[NPB][DIN + 4];  // padded, 16B-aligned rows
    for (int i = threadIdx.x; i < DIN * 64; i += 256) Ws[i] = W[i];

    const int q = threadIdx.x & (DQ - 1);
    const int ln = threadIdx.x / DQ;
    const int n = blockIdx.x * NPB + ln;
    const int lane = threadIdx.x & 63;
    const int sub = lane & ~(DQ - 1);

    if (n < nNodes) {
        const float4* __restrict__ h4 = (const float4*)hin;
        float4 acc = make_float4(0.f, 0.f, 0.f, 0.f);
        const int e0 = off[n];
        const int e1 = off[n + 1];
        for (int base = e0; base < e1; base += DQ) {
            const int me = base + q;
            int src = 0;
            float w = 0.f;
            if (me < e1) {
                src = recs[me];
                w = dinv[src];
            }
            const int m = min(DQ, e1 - base);
            for (int j = 0; j < m; ++j) {
                const int s = __shfl(src, sub + j);
                const float wj = __shfl(w, sub + j);
                const float4 hv = h4[s * DQ + q];
                acc.x += wj * hv.x;
                acc.y += wj * hv.y;
                acc.z += wj * hv.z;
                acc.w += wj * hv.w;
            }
        }
        const float dn = dinv[n];
        acc.x *= dn;
        acc.y *= dn;
        acc.z *= dn;
        acc.w *= dn;
        if (WRITE_H) ((float4*)hout)[n * DQ + q] = acc;
        *(float4*)&hs[ln][q * 4] = acc;
    }
    __syncthreads();

    const float4* W4 = (const float4*)Ws;
    if (DQ == 16) {
        // thread: node ln (16/block), output quad q (16/node)
        if (n >= nNodes) return;
        float4* o = (float4*)(out + (size_t)n * 64) + q;
        float4 a = *o;
        const float* hr = hs[ln];
#pragma unroll
        for (int i = 0; i < 64; i += 4) {
            const float4 hv = *(const float4*)(hr + i);
            const float4 w0 = W4[(i + 0) * 16 + q];
            const float4 w1 = W4[(i + 1) * 16 + q];
            const float4 w2 = W4[(i + 2) * 16 + q];
            const float4 w3 = W4[(i + 3) * 16 + q];
            a.x += hv.x * w0.x + hv.y * w1.x + hv.z * w2.x + hv.w * w3.x;
            a.y += hv.x * w0.y + hv.y * w1.y + hv.z * w2.y + hv.w * w3.y;
            a.z += hv.x * w0.z + hv.y * w1.z + hv.z * w2.z + hv.w * w3.z;
            a.w += hv.x * w0.w + hv.y * w1.w + hv.z * w2.w + hv.w * w3.w;
        }
        if (RELU) {
            a.x = fmaxf(a.x, 0.f);
            a.y = fmaxf(a.y, 0.f);
            a.z = fmaxf(a.z, 0.f);
            a.w = fmaxf(a.w, 0.f);
        }
        *o = a;
    } else {
        // DQ==4: thread: node ln (64/block), 16 output cols at oq*16 (oq = q)
        if (n >= nNodes) return;
        float4* o = (float4*)(out + (size_t)n * 64) + q * 4;
        float4 a0 = o[0], a1 = o[1], a2 = o[2], a3 = o[3];
        const float* hr = hs[ln];
#pragma unroll
        for (int i = 0; i < DIN; ++i) {
            const float hv = hr[i];
            const float4 w0 = W4[i * 16 + q * 4 + 0];
            const float4 w1 = W4[i * 16 + q * 4 + 1];
            const float4 w2 = W4[i * 16 + q * 4 + 2];
            const float4 w3 = W4[i * 16 + q * 4 + 3];
            a0.x += hv * w0.x; a0.y += hv * w0.y; a0.z += hv * w0.z; a0.w += hv * w0.w;
            a1.x += hv * w1.x; a1.y += hv * w1.y; a1.z += hv * w1.z; a1.w += hv * w1.w;
            a2.x += hv * w2.x; a2.y += hv * w2.y; a2.z += hv * w2.z; a2.w += hv * w2.w;
            a3.x += hv * w3.x; a3.y += hv * w3.y; a3.z += hv * w3.z; a3.w += hv * w3.w;
        }
        if (RELU) {
            a0.x = fmaxf(a0.x, 0.f); a0.y = fmaxf(a0.y, 0.f); a0.z = fmaxf(a0.z, 0.f); a0.w = fmaxf(a0.w, 0.f);
            a1.x = fmaxf(a1.x, 0.f); a1.y = fmaxf(a1.y, 0.f); a1.z = fmaxf(a1.z, 0.f); a1.w = fmaxf(a1.w, 0.f);
            a2.x = fmaxf(a2.x, 0.f); a2.y = fmaxf(a2.y, 0.f); a2.z = fmaxf(a2.z, 0.f); a2.w = fmaxf(a2.w, 0.f);
            a3.x = fmaxf(a3.x, 0.f); a3.y = fmaxf(a3.y, 0.f); a3.z = fmaxf(a3.z, 0.f); a3.w = fmaxf(a3.w, 0.f);
        }
        o[0] = a0; o[1] = a1; o[2] = a2; o[3] = a3;
    }
}

// ---------------- standalone dense (INIT terms) ----------------

template <int DIN, bool INIT, bool RELU>
__global__ __launch_bounds__(256) void gemm64_kernel(const float* __restrict__ h,
                                                     const float* __restrict__ W,
                                                     const float* __restrict__ b,
                                                     float* __restrict__ out, int nNodes) {
    __shared__ float Ws[DIN * 64];
    __shared__ float bs[64];
    for (int i = threadIdx.x; i < DIN * 64; i += 256) Ws[i] = W[i];
    if (threadIdx.x < 64) bs[threadIdx.x] = b[threadIdx.x];
    __syncthreads();
    const int q = threadIdx.x & 15;
    const int n = blockIdx.x * 16 + (threadIdx.x >> 4);
    if (n >= nNodes) return;
    const float4* __restrict__ h4 = (const float4*)(h + (size_t)n * DIN);
    float4* o = (float4*)(out + (size_t)n * 64) + q;
    float4 acc;
    if (INIT)
        acc = make_float4(bs[q * 4 + 0], bs[q * 4 + 1], bs[q * 4 + 2], bs[q * 4 + 3]);
    else
        acc = *o;
    const float4* W4 = (const float4*)Ws;
#pragma unroll
    for (int i4 = 0; i4 < DIN / 4; ++i4) {
        float4 hv = h4[i4];
        float4 w0 = W4[(i4 * 4 + 0) * 16 + q];
        float4 w1 = W4[(i4 * 4 + 1) * 16 + q];
        float4 w2 = W4[(i4 * 4 + 2) * 16 + q];
        float4 w3 = W4[(i4 * 4 + 3) * 16 + q];
        acc.x += hv.x * w0.x + hv.y * w1.x + hv.z * w2.x + hv.w * w3.x;
        acc.y += hv.x * w0.y + hv.y * w1.y + hv.z * w2.y + hv.w * w3.y;
        acc.z += hv.x * w0.z + hv.y * w1.z + hv.z * w2.z + hv.w * w3.z;
        acc.w += hv.x * w0.w + hv.y * w1.w + hv.z * w2.w + hv.w * w3.w;
    }
    if (RELU) {
        acc.x = fmaxf(acc.x, 0.f);
        acc.y = fmaxf(acc.y, 0.f);
        acc.z = fmaxf(acc.z, 0.f);
        acc.w = fmaxf(acc.w, 0.f);
    }
    *o = acc;
}

// DOUT=4 (final layer). MODE: 0 = out = h@W; 1 = out += h@W; 2 = out = h@W + b + add.
template <int MODE>
__global__ __launch_bounds__(256) void gemm4_kernel(const float* __restrict__ h,
                                                    const float* __restrict__ W,
                                                    const float* __restrict__ b,
                                                    const float* __restrict__ add,
                                                    float* __restrict__ out, int nNodes) {
    __shared__ float Ws[64 * 4];
    __shared__ float bs[4];
    if (threadIdx.x < 256) Ws[threadIdx.x] = W[threadIdx.x];
    if (MODE == 2 && threadIdx.x < 4) bs[threadIdx.x] = b[threadIdx.x];
    __syncthreads();
    const int q = threadIdx.x & 3;
    const int n = blockIdx.x * 64 + (threadIdx.x >> 2);
    if (n >= nNodes) return;
    const float4* __restrict__ h4 = (const float4*)(h + (size_t)n * 64);
    float acc = 0.f;
#pragma unroll
    for (int i4 = 0; i4 < 16; ++i4) {
        float4 hv = h4[i4];
        acc += hv.x * Ws[(i4 * 4 + 0) * 4 + q] + hv.y * Ws[(i4 * 4 + 1) * 4 + q] +
               hv.z * Ws[(i4 * 4 + 2) * 4 + q] + hv.w * Ws[(i4 * 4 + 3) * 4 + q];
    }
    const int idx = n * 4 + q;
    if (MODE == 0)
        out[idx] = acc;
    else if (MODE == 1)
        out[idx] += acc;
    else
        out[idx] = acc + bs[q] + add[idx];
}

// ---------------- host ----------------

extern "C" void kernel_launch(void* const* d_in, const int* in_sizes, int n_in,
                              void* d_out, int out_size, void* d_ws, size_t ws_size,
                              hipStream_t stream) {
    const float* x = (const float*)d_in[0];
    const int* ei = (const int*)d_in[1];  // [2][E]: row=ei[e], col=ei[E+e]
    const float* W[5] = {(const float*)d_in[2], (const float*)d_in[4], (const float*)d_in[6],
                         (const float*)d_in[8], (const float*)d_in[10]};
    const float* bb[5] = {(const float*)d_in[3], (const float*)d_in[5], (const float*)d_in[7],
                          (const float*)d_in[9], (const float*)d_in[11]};
    const int E = in_sizes[1] / 2;   // 800000
    const int N = in_sizes[0] / 16;  // 50000
    float* outp = (float*)d_out;

    char* p = (char*)d_ws;
    auto alloc = [&](size_t bytes) {
        char* r = p;
        p += (bytes + 255) & ~size_t(255);
        return r;
    };
    const int nb = (N + 255) / 256;
    int* cnt = (int*)alloc((size_t)N * 4);
    int* off = (int*)alloc((size_t)(N + 1) * 4);
    int* cursor = (int*)alloc((size_t)N * 4);
    float* dinv = (float*)alloc((size_t)N * 4);
    int* bsum = (int*)alloc((size_t)nb * 4);
    int* bbase = (int*)alloc((size_t)nb * 4);
    int* recs = (int*)alloc((size_t)E * 4);
    float* A = (float*)alloc((size_t)N * 64 * 4);
    float* B = (float*)alloc((size_t)N * 64 * 4);
    float* C = (float*)alloc((size_t)N * 64 * 4);
    float* O = (float*)alloc((size_t)N * 64 * 4);
    float* T1 = (float*)alloc((size_t)N * 4 * 4);
    float* T2 = (float*)alloc((size_t)N * 4 * 4);

    hipMemsetAsync(cnt, 0, (size_t)N * 4, stream);
    hipMemsetAsync(cursor, 0, (size_t)N * 4, stream);
    const int eb = (E + 255) / 256;
    count_kernel<<<eb, 256, 0, stream>>>(ei + E, cnt, E);
    scan_block_kernel<<<nb, 256, 0, stream>>>(cnt, off, bsum, N);
    scan_bsum_kernel<<<1, 256, 0, stream>>>(bsum, bbase, nb);
    scan_apply_kernel<<<nb, 256, 0, stream>>>(off, bbase, N, E);
    dinv_kernel<<<nb, 256, 0, stream>>>(cnt, dinv, N);
    scatter_kernel<<<eb, 256, 0, stream>>>(ei, ei + E, off, cursor, recs, E);

    const int g64 = (N + 15) / 16;   // 16 nodes/block
    const int g4 = (N + 63) / 64;
    const int gf16 = (N + 15) / 16;  // fused DQ=16: 16 nodes/block
    const int gf4 = (N + 63) / 64;   // fused DQ=4: 64 nodes/block
    const int p1 = (N + 255) / 256;

    // Layer 0: x(16) -> O; hops propagate 16-dim x, fused with 16->64 GEMM
    gemm64_kernel<16, true, false><<<g64, 256, 0, stream>>>(x, W[0] + 0 * 1024, bb[0], O, N);
    prop_gemm64_kernel<4, true, false><<<gf4, 256, 0, stream>>>(off, recs, dinv, x, B,
                                                                W[0] + 1 * 1024, O, N);
    prop_gemm64_kernel<4, true, false><<<gf4, 256, 0, stream>>>(off, recs, dinv, B, C,
                                                                W[0] + 2 * 1024, O, N);
    prop_gemm64_kernel<4, false, true><<<gf4, 256, 0, stream>>>(off, recs, dinv, C, nullptr,
                                                                W[0] + 3 * 1024, O, N);

    // Layers 1-3: 64 -> 64, ping-pong cur/nxt between O and A
    float* cur = O;
    float* nxt = A;
    for (int l = 1; l <= 3; ++l) {
        const float* Wl = W[l];
        gemm64_kernel<64, true, false><<<g64, 256, 0, stream>>>(cur, Wl + 0 * 4096, bb[l], nxt, N);
        prop_gemm64_kernel<16, true, false><<<gf16, 256, 0, stream>>>(off, recs, dinv, cur, B,
                                                                      Wl + 1 * 4096, nxt, N);
        prop_gemm64_kernel<16, true, false><<<gf16, 256, 0, stream>>>(off, recs, dinv, B, C,
                                                                      Wl + 2 * 4096, nxt, N);
        prop_gemm64_kernel<16, false, true><<<gf16, 256, 0, stream>>>(off, recs, dinv, C, nullptr,
                                                                      Wl + 3 * 4096, nxt, N);
        float* t = cur;
        cur = nxt;
        nxt = t;
    }

    // Layer 4 via Horner on the feature-projected (4-dim) signal:
    // out = cur@W0 + A(cur@W1 + A(cur@W2 + A(cur@W3))) + b
    gemm4_kernel<0><<<g4, 256, 0, stream>>>(cur, W[4] + 3 * 256, nullptr, nullptr, T1, N);
    prop1_kernel<<<p1, 256, 0, stream>>>(off, recs, dinv, T1, T2, N);
    gemm4_kernel<1><<<g4, 256, 0, stream>>>(cur, W[4] + 2 * 256, nullptr, nullptr, T2, N);
    prop1_kernel<<<p1, 256, 0, stream>>>(off, recs, dinv, T2, T1, N);
    gemm4_kernel<1><<<g4, 256, 0, stream>>>(cur, W[4] + 1 * 256, nullptr, nullptr, T1, N);
    prop1_kernel<<<p1, 256, 0, stream>>>(off, recs, dinv, T1, T2, N);
    gemm4_kernel<2><<<g4, 256, 0, stream>>>(cur, W[4] + 0 * 256, bb[4], T2, outp, N);
}

// Round 4
// 552.308 us; speedup vs baseline: 1.1679x; 1.1679x over previous
//
#include <hip/hip_runtime.h>

// ---------------- CSR build ----------------

// Count + per-edge rank (return value of the atomic).
__global__ __launch_bounds__(256) void count_rank_kernel(const int* __restrict__ col,
                                                         int* __restrict__ cnt,
                                                         int* __restrict__ rank, int E) {
    int e = blockIdx.x * 256 + threadIdx.x;
    if (e < E) rank[e] = atomicAdd(&cnt[col[e]], 1);
}

// Hierarchical scan, stage 1: per-block exclusive scan + block totals.
__global__ __launch_bounds__(256) void scan_block_kernel(const int* __restrict__ cnt,
                                                         int* __restrict__ off,
                                                         int* __restrict__ bsum, int n) {
    const int gid = blockIdx.x * 256 + threadIdx.x;
    const int v = (gid < n) ? cnt[gid] : 0;
    const int lane = threadIdx.x & 63, w = threadIdx.x >> 6;
    int x = v;
#pragma unroll
    for (int d = 1; d < 64; d <<= 1) {
        int t = __shfl_up(x, d);
        if (lane >= d) x += t;
    }
    __shared__ int wt[4];
    if (lane == 63) wt[w] = x;
    __syncthreads();
    int base = 0;
#pragma unroll
    for (int i = 0; i < 3; ++i)
        if (i < w) base += wt[i];
    const int incl = base + x;
    if (gid < n) off[gid] = incl - v;
    if (threadIdx.x == 255) bsum[blockIdx.x] = incl;
}

__global__ __launch_bounds__(256) void scan_bsum_kernel(const int* __restrict__ bsum,
                                                        int* __restrict__ bbase, int nb) {
    const int tid = threadIdx.x;
    const int v = (tid < nb) ? bsum[tid] : 0;
    const int lane = tid & 63, w = tid >> 6;
    int x = v;
#pragma unroll
    for (int d = 1; d < 64; d <<= 1) {
        int t = __shfl_up(x, d);
        if (lane >= d) x += t;
    }
    __shared__ int wt[4];
    if (lane == 63) wt[w] = x;
    __syncthreads();
    int base = 0;
#pragma unroll
    for (int i = 0; i < 3; ++i)
        if (i < w) base += wt[i];
    if (tid < nb) bbase[tid] = base + x - v;
}

__global__ __launch_bounds__(256) void scan_apply_kernel(int* __restrict__ off,
                                                         const int* __restrict__ bbase,
                                                         int n, int E) {
    const int gid = blockIdx.x * 256 + threadIdx.x;
    if (gid < n) off[gid] += bbase[blockIdx.x];
    if (gid == n) off[n] = E;
}

__global__ __launch_bounds__(256) void dinv_kernel(const int* __restrict__ cnt,
                                                   float* __restrict__ dinv, int n) {
    int i = blockIdx.x * 256 + threadIdx.x;
    if (i < n) {
        int c = cnt[i];
        dinv[i] = (c > 0) ? 1.0f / sqrtf((float)c) : 0.0f;
    }
}

// Scatter edge -> (src, norm) record at its CSR slot. No atomics (rank precomputed).
__global__ __launch_bounds__(256) void scatter_kernel(const int* __restrict__ row,
                                                      const int* __restrict__ col,
                                                      const int* __restrict__ off,
                                                      const int* __restrict__ rank,
                                                      const float* __restrict__ dinv,
                                                      int2* __restrict__ recs, int E) {
    int e = blockIdx.x * 256 + threadIdx.x;
    if (e >= E) return;
    const int r = row[e], c = col[e];
    const int pos = off[c] + rank[e];
    recs[pos] = make_int2(r, __float_as_int(dinv[r] * dinv[c]));
}

// ---------------- fused prop + GEMM(DIN->64) accumulate ----------------
// DQ lanes per node (DIN = 4*DQ). Per-lane gather (records broadcast across the
// node's lanes by the cache), 4x unrolled independent gathers. Propagated row goes
// to registers -> (optional) hout -> LDS; then block-local GEMM accumulates into out.

template <int DQ, bool WRITE_H, bool RELU>
__global__ __launch_bounds__(256) void prop_gemm64_kernel(
    const int* __restrict__ off, const int2* __restrict__ recs,
    const float* __restrict__ hin, float* __restrict__ hout,
    const float* __restrict__ W, float* __restrict__ out, int nNodes) {
    constexpr int DIN = DQ * 4;
    constexpr int NPB = 256 / DQ;  // nodes per block
    __shared__ __align__(16) float Ws[DIN * 64];
    __shared__ __align__(16) float hs[NPB][DIN + 4];
    for (int i = threadIdx.x; i < DIN * 64; i += 256) Ws[i] = W[i];

    const int q = threadIdx.x & (DQ - 1);
    const int ln = threadIdx.x / DQ;
    const int n = blockIdx.x * NPB + ln;

    if (n < nNodes) {
        const float4* __restrict__ h4 = (const float4*)hin;
        float4 acc = make_float4(0.f, 0.f, 0.f, 0.f);
        int e = off[n];
        const int e1 = off[n + 1];
        for (; e + 4 <= e1; e += 4) {
            const int2 r0 = recs[e + 0];
            const int2 r1 = recs[e + 1];
            const int2 r2 = recs[e + 2];
            const int2 r3 = recs[e + 3];
            const float4 a = h4[r0.x * DQ + q];
            const float4 b = h4[r1.x * DQ + q];
            const float4 c = h4[r2.x * DQ + q];
            const float4 d = h4[r3.x * DQ + q];
            const float w0 = __int_as_float(r0.y), w1 = __int_as_float(r1.y);
            const float w2 = __int_as_float(r2.y), w3 = __int_as_float(r3.y);
            acc.x += w0 * a.x + w1 * b.x + w2 * c.x + w3 * d.x;
            acc.y += w0 * a.y + w1 * b.y + w2 * c.y + w3 * d.y;
            acc.z += w0 * a.z + w1 * b.z + w2 * c.z + w3 * d.z;
            acc.w += w0 * a.w + w1 * b.w + w2 * c.w + w3 * d.w;
        }
        for (; e < e1; ++e) {
            const int2 r = recs[e];
            const float ww = __int_as_float(r.y);
            const float4 hv = h4[r.x * DQ + q];
            acc.x += ww * hv.x;
            acc.y += ww * hv.y;
            acc.z += ww * hv.z;
            acc.w += ww * hv.w;
        }
        if (WRITE_H) ((float4*)hout)[n * DQ + q] = acc;
        *(float4*)&hs[ln][q * 4] = acc;
    }
    __syncthreads();

    const float4* W4 = (const float4*)Ws;
    if (n >= nNodes) return;
    if (DQ == 16) {
        // thread: node ln (16/block), output quad q (16/node)
        float4* o = (float4*)(out + (size_t)n * 64) + q;
        float4 a = *o;
        const float* hr = hs[ln];
#pragma unroll
        for (int i = 0; i < 64; i += 4) {
            const float4 hv = *(const float4*)(hr + i);
            const float4 w0 = W4[(i + 0) * 16 + q];
            const float4 w1 = W4[(i + 1) * 16 + q];
            const float4 w2 = W4[(i + 2) * 16 + q];
            const float4 w3 = W4[(i + 3) * 16 + q];
            a.x += hv.x * w0.x + hv.y * w1.x + hv.z * w2.x + hv.w * w3.x;
            a.y += hv.x * w0.y + hv.y * w1.y + hv.z * w2.y + hv.w * w3.y;
            a.z += hv.x * w0.z + hv.y * w1.z + hv.z * w2.z + hv.w * w3.z;
            a.w += hv.x * w0.w + hv.y * w1.w + hv.z * w2.w + hv.w * w3.w;
        }
        if (RELU) {
            a.x = fmaxf(a.x, 0.f);
            a.y = fmaxf(a.y, 0.f);
            a.z = fmaxf(a.z, 0.f);
            a.w = fmaxf(a.w, 0.f);
        }
        *o = a;
    } else {
        // DQ==4: thread: node ln (64/block), 16 output cols at q*16
        float4* o = (float4*)(out + (size_t)n * 64) + q * 4;
        float4 a0 = o[0], a1 = o[1], a2 = o[2], a3 = o[3];
        const float* hr = hs[ln];
#pragma unroll
        for (int i = 0; i < DIN; ++i) {
            const float hv = hr[i];
            const float4 w0 = W4[i * 16 + q * 4 + 0];
            const float4 w1 = W4[i * 16 + q * 4 + 1];
            const float4 w2 = W4[i * 16 + q * 4 + 2];
            const float4 w3 = W4[i * 16 + q * 4 + 3];
            a0.x += hv * w0.x; a0.y += hv * w0.y; a0.z += hv * w0.z; a0.w += hv * w0.w;
            a1.x += hv * w1.x; a1.y += hv * w1.y; a1.z += hv * w1.z; a1.w += hv * w1.w;
            a2.x += hv * w2.x; a2.y += hv * w2.y; a2.z += hv * w2.z; a2.w += hv * w2.w;
            a3.x += hv * w3.x; a3.y += hv * w3.y; a3.z += hv * w3.z; a3.w += hv * w3.w;
        }
        if (RELU) {
            a0.x = fmaxf(a0.x, 0.f); a0.y = fmaxf(a0.y, 0.f); a0.z = fmaxf(a0.z, 0.f); a0.w = fmaxf(a0.w, 0.f);
            a1.x = fmaxf(a1.x, 0.f); a1.y = fmaxf(a1.y, 0.f); a1.z = fmaxf(a1.z, 0.f); a1.w = fmaxf(a1.w, 0.f);
            a2.x = fmaxf(a2.x, 0.f); a2.y = fmaxf(a2.y, 0.f); a2.z = fmaxf(a2.z, 0.f); a2.w = fmaxf(a2.w, 0.f);
            a3.x = fmaxf(a3.x, 0.f); a3.y = fmaxf(a3.y, 0.f); a3.z = fmaxf(a3.z, 0.f); a3.w = fmaxf(a3.w, 0.f);
        }
        o[0] = a0; o[1] = a1; o[2] = a2; o[3] = a3;
    }
}

// ---------------- standalone dense (k=0 INIT terms) ----------------

template <int DIN, bool INIT, bool RELU>
__global__ __launch_bounds__(256) void gemm64_kernel(const float* __restrict__ h,
                                                     const float* __restrict__ W,
                                                     const float* __restrict__ b,
                                                     float* __restrict__ out, int nNodes) {
    __shared__ float Ws[DIN * 64];
    __shared__ float bs[64];
    for (int i = threadIdx.x; i < DIN * 64; i += 256) Ws[i] = W[i];
    if (threadIdx.x < 64) bs[threadIdx.x] = b[threadIdx.x];
    __syncthreads();
    const int q = threadIdx.x & 15;
    const int n = blockIdx.x * 16 + (threadIdx.x >> 4);
    if (n >= nNodes) return;
    const float4* __restrict__ h4 = (const float4*)(h + (size_t)n * DIN);
    float4* o = (float4*)(out + (size_t)n * 64) + q;
    float4 acc;
    if (INIT)
        acc = make_float4(bs[q * 4 + 0], bs[q * 4 + 1], bs[q * 4 + 2], bs[q * 4 + 3]);
    else
        acc = *o;
    const float4* W4 = (const float4*)Ws;
#pragma unroll
    for (int i4 = 0; i4 < DIN / 4; ++i4) {
        float4 hv = h4[i4];
        float4 w0 = W4[(i4 * 4 + 0) * 16 + q];
        float4 w1 = W4[(i4 * 4 + 1) * 16 + q];
        float4 w2 = W4[(i4 * 4 + 2) * 16 + q];
        float4 w3 = W4[(i4 * 4 + 3) * 16 + q];
        acc.x += hv.x * w0.x + hv.y * w1.x + hv.z * w2.x + hv.w * w3.x;
        acc.y += hv.x * w0.y + hv.y * w1.y + hv.z * w2.y + hv.w * w3.y;
        acc.z += hv.x * w0.z + hv.y * w1.z + hv.z * w2.z + hv.w * w3.z;
        acc.w += hv.x * w0.w + hv.y * w1.w + hv.z * w2.w + hv.w * w3.w;
    }
    if (RELU) {
        acc.x = fmaxf(acc.x, 0.f);
        acc.y = fmaxf(acc.y, 0.f);
        acc.z = fmaxf(acc.z, 0.f);
        acc.w = fmaxf(acc.w, 0.f);
    }
    *o = acc;
}

// ---------------- layer 4: all four 4-dim projections in one pass ----------------
// P_k = cur @ W[4][k]   (k = 0..3). 4 lanes/node, lane k computes P_k[n][0..3].

__global__ __launch_bounds__(256) void proj4_kernel(const float* __restrict__ h,
                                                    const float* __restrict__ W,
                                                    float* __restrict__ P0,
                                                    float* __restrict__ P1,
                                                    float* __restrict__ P2,
                                                    float* __restrict__ P3, int nNodes) {
    __shared__ float Ws[4 * 64 * 4];
    for (int i = threadIdx.x; i < 1024; i += 256) Ws[i] = W[i];
    __syncthreads();
    const int k = threadIdx.x & 3;
    const int n = blockIdx.x * 64 + (threadIdx.x >> 2);
    if (n >= nNodes) return;
    const float4* __restrict__ h4 = (const float4*)(h + (size_t)n * 64);
    const float4* W4 = (const float4*)(Ws + k * 256);  // W[k]: 64 rows x 4 cols
    float4 acc = make_float4(0.f, 0.f, 0.f, 0.f);
#pragma unroll
    for (int i4 = 0; i4 < 16; ++i4) {
        const float4 hv = h4[i4];
        const float4 w0 = W4[i4 * 4 + 0];
        const float4 w1 = W4[i4 * 4 + 1];
        const float4 w2 = W4[i4 * 4 + 2];
        const float4 w3 = W4[i4 * 4 + 3];
        acc.x += hv.x * w0.x + hv.y * w1.x + hv.z * w2.x + hv.w * w3.x;
        acc.y += hv.x * w0.y + hv.y * w1.y + hv.z * w2.y + hv.w * w3.y;
        acc.z += hv.x * w0.z + hv.y * w1.z + hv.z * w2.z + hv.w * w3.z;
        acc.w += hv.x * w0.w + hv.y * w1.w + hv.z * w2.w + hv.w * w3.w;
    }
    float4* dst = (k == 0) ? (float4*)P0 : (k == 1) ? (float4*)P1 : (k == 2) ? (float4*)P2
                                                                             : (float4*)P3;
    dst[n] = acc;
}

// Horner step on 4-dim signals: out[n] = P[n] (+bias) + sum_e norm_e * U[src_e]
template <bool FINAL>
__global__ __launch_bounds__(256) void prop1_add_kernel(const int* __restrict__ off,
                                                        const int2* __restrict__ recs,
                                                        const float* __restrict__ Uin,
                                                        const float* __restrict__ P,
                                                        const float* __restrict__ b,
                                                        float* __restrict__ out, int nNodes) {
    const int n = blockIdx.x * 256 + threadIdx.x;
    if (n >= nNodes) return;
    const float4* __restrict__ u4 = (const float4*)Uin;
    float4 acc = ((const float4*)P)[n];
    if (FINAL) {
        const float4 bv = *(const float4*)b;
        acc.x += bv.x;
        acc.y += bv.y;
        acc.z += bv.z;
        acc.w += bv.w;
    }
    int e = off[n];
    const int e1 = off[n + 1];
    for (; e + 4 <= e1; e += 4) {
        const int2 r0 = recs[e + 0];
        const int2 r1 = recs[e + 1];
        const int2 r2 = recs[e + 2];
        const int2 r3 = recs[e + 3];
        const float4 a = u4[r0.x], bb = u4[r1.x], c = u4[r2.x], d = u4[r3.x];
        const float w0 = __int_as_float(r0.y), w1 = __int_as_float(r1.y);
        const float w2 = __int_as_float(r2.y), w3 = __int_as_float(r3.y);
        acc.x += w0 * a.x + w1 * bb.x + w2 * c.x + w3 * d.x;
        acc.y += w0 * a.y + w1 * bb.y + w2 * c.y + w3 * d.y;
        acc.z += w0 * a.z + w1 * bb.z + w2 * c.z + w3 * d.z;
        acc.w += w0 * a.w + w1 * bb.w + w2 * c.w + w3 * d.w;
    }
    for (; e < e1; ++e) {
        const int2 r = recs[e];
        const float ww = __int_as_float(r.y);
        const float4 hv = u4[r.x];
        acc.x += ww * hv.x;
        acc.y += ww * hv.y;
        acc.z += ww * hv.z;
        acc.w += ww * hv.w;
    }
    ((float4*)out)[n] = acc;
}

// ---------------- host ----------------

extern "C" void kernel_launch(void* const* d_in, const int* in_sizes, int n_in,
                              void* d_out, int out_size, void* d_ws, size_t ws_size,
                              hipStream_t stream) {
    const float* x = (const float*)d_in[0];
    const int* ei = (const int*)d_in[1];  // [2][E]: row=ei[e], col=ei[E+e]
    const float* W[5] = {(const float*)d_in[2], (const float*)d_in[4], (const float*)d_in[6],
                         (const float*)d_in[8], (const float*)d_in[10]};
    const float* bb[5] = {(const float*)d_in[3], (const float*)d_in[5], (const float*)d_in[7],
                          (const float*)d_in[9], (const float*)d_in[11]};
    const int E = in_sizes[1] / 2;   // 800000
    const int N = in_sizes[0] / 16;  // 50000
    float* outp = (float*)d_out;

    char* p = (char*)d_ws;
    auto alloc = [&](size_t bytes) {
        char* r = p;
        p += (bytes + 255) & ~size_t(255);
        return r;
    };
    const int nb = (N + 255) / 256;
    int* cnt = (int*)alloc((size_t)N * 4);
    int* off = (int*)alloc((size_t)(N + 1) * 4);
    float* dinv = (float*)alloc((size_t)N * 4);
    int* bsum = (int*)alloc((size_t)nb * 4);
    int* bbase = (int*)alloc((size_t)nb * 4);
    int* rank = (int*)alloc((size_t)E * 4);
    int2* recs = (int2*)alloc((size_t)E * 8);
    float* A = (float*)alloc((size_t)N * 64 * 4);
    float* B = (float*)alloc((size_t)N * 64 * 4);
    float* C = (float*)alloc((size_t)N * 64 * 4);
    float* O = (float*)alloc((size_t)N * 64 * 4);
    float* P0 = (float*)alloc((size_t)N * 4 * 4);
    float* P1 = (float*)alloc((size_t)N * 4 * 4);
    float* P2 = (float*)alloc((size_t)N * 4 * 4);
    float* P3 = (float*)alloc((size_t)N * 4 * 4);
    float* Ua = (float*)alloc((size_t)N * 4 * 4);
    float* Ub = (float*)alloc((size_t)N * 4 * 4);

    hipMemsetAsync(cnt, 0, (size_t)N * 4, stream);
    const int eb = (E + 255) / 256;
    count_rank_kernel<<<eb, 256, 0, stream>>>(ei + E, cnt, rank, E);
    scan_block_kernel<<<nb, 256, 0, stream>>>(cnt, off, bsum, N);
    scan_bsum_kernel<<<1, 256, 0, stream>>>(bsum, bbase, nb);
    scan_apply_kernel<<<nb, 256, 0, stream>>>(off, bbase, N, E);
    dinv_kernel<<<nb, 256, 0, stream>>>(cnt, dinv, N);
    scatter_kernel<<<eb, 256, 0, stream>>>(ei, ei + E, off, rank, dinv, recs, E);

    const int g64 = (N + 15) / 16;   // 16 nodes/block
    const int gf16 = (N + 15) / 16;  // fused DQ=16
    const int gf4 = (N + 63) / 64;   // fused DQ=4
    const int p1 = (N + 255) / 256;

    // Layer 0: x(16) -> O; hops on 16-dim x fused with 16->64 GEMM accumulate
    gemm64_kernel<16, true, false><<<g64, 256, 0, stream>>>(x, W[0] + 0 * 1024, bb[0], O, N);
    prop_gemm64_kernel<4, true, false><<<gf4, 256, 0, stream>>>(off, recs, x, B,
                                                                W[0] + 1 * 1024, O, N);
    prop_gemm64_kernel<4, true, false><<<gf4, 256, 0, stream>>>(off, recs, B, C,
                                                                W[0] + 2 * 1024, O, N);
    prop_gemm64_kernel<4, false, true><<<gf4, 256, 0, stream>>>(off, recs, C, nullptr,
                                                                W[0] + 3 * 1024, O, N);

    // Layers 1-3: 64 -> 64, ping-pong cur/nxt between O and A
    float* cur = O;
    float* nxt = A;
    for (int l = 1; l <= 3; ++l) {
        const float* Wl = W[l];
        gemm64_kernel<64, true, false><<<g64, 256, 0, stream>>>(cur, Wl + 0 * 4096, bb[l], nxt, N);
        prop_gemm64_kernel<16, true, false><<<gf16, 256, 0, stream>>>(off, recs, cur, B,
                                                                      Wl + 1 * 4096, nxt, N);
        prop_gemm64_kernel<16, true, false><<<gf16, 256, 0, stream>>>(off, recs, B, C,
                                                                      Wl + 2 * 4096, nxt, N);
        prop_gemm64_kernel<16, false, true><<<gf16, 256, 0, stream>>>(off, recs, C, nullptr,
                                                                      Wl + 3 * 4096, nxt, N);
        float* t = cur;
        cur = nxt;
        nxt = t;
    }

    // Layer 4: P_k = cur@W4_k in one read of cur, then Horner on 4-dim signals:
    // out = P0 + b + A(P1 + A(P2 + A*P3))
    proj4_kernel<<<gf4, 256, 0, stream>>>(cur, W[4], P0, P1, P2, P3, N);
    prop1_add_kernel<false><<<p1, 256, 0, stream>>>(off, recs, P3, P2, nullptr, Ua, N);
    prop1_add_kernel<false><<<p1, 256, 0, stream>>>(off, recs, Ua, P1, nullptr, Ub, N);
    prop1_add_kernel<true><<<p1, 256, 0, stream>>>(off, recs, Ub, P0, bb[4], outp, N);
}

// Round 5
// 450.828 us; speedup vs baseline: 1.4308x; 1.2251x over previous
//
#include <hip/hip_runtime.h>
#include <hip/hip_fp16.h>

// ---------------- fp16 helpers ----------------
union H2I { int i; __half2 h; };
static __device__ inline float2 i2f2(int v) {
    H2I u; u.i = v; return __half22float2(u.h);
}
static __device__ inline int f2i2(float a, float b) {
    H2I u; u.h = __floats2half2_rn(a, b); return u.i;
}

// ---------------- CSR build ----------------

__global__ __launch_bounds__(256) void count_rank_kernel(const int* __restrict__ col,
                                                         int* __restrict__ cnt,
                                                         int* __restrict__ rank, int E) {
    int e = blockIdx.x * 256 + threadIdx.x;
    if (e < E) rank[e] = atomicAdd(&cnt[col[e]], 1);
}

__global__ __launch_bounds__(256) void scan_block_kernel(const int* __restrict__ cnt,
                                                         int* __restrict__ off,
                                                         int* __restrict__ bsum, int n) {
    const int gid = blockIdx.x * 256 + threadIdx.x;
    const int v = (gid < n) ? cnt[gid] : 0;
    const int lane = threadIdx.x & 63, w = threadIdx.x >> 6;
    int x = v;
#pragma unroll
    for (int d = 1; d < 64; d <<= 1) {
        int t = __shfl_up(x, d);
        if (lane >= d) x += t;
    }
    __shared__ int wt[4];
    if (lane == 63) wt[w] = x;
    __syncthreads();
    int base = 0;
#pragma unroll
    for (int i = 0; i < 3; ++i)
        if (i < w) base += wt[i];
    const int incl = base + x;
    if (gid < n) off[gid] = incl - v;
    if (threadIdx.x == 255) bsum[blockIdx.x] = incl;
}

__global__ __launch_bounds__(256) void scan_bsum_kernel(const int* __restrict__ bsum,
                                                        int* __restrict__ bbase, int nb) {
    const int tid = threadIdx.x;
    const int v = (tid < nb) ? bsum[tid] : 0;
    const int lane = tid & 63, w = tid >> 6;
    int x = v;
#pragma unroll
    for (int d = 1; d < 64; d <<= 1) {
        int t = __shfl_up(x, d);
        if (lane >= d) x += t;
    }
    __shared__ int wt[4];
    if (lane == 63) wt[w] = x;
    __syncthreads();
    int base = 0;
#pragma unroll
    for (int i = 0; i < 3; ++i)
        if (i < w) base += wt[i];
    if (tid < nb) bbase[tid] = base + x - v;
}

__global__ __launch_bounds__(256) void scan_apply_kernel(int* __restrict__ off,
                                                         const int* __restrict__ bbase,
                                                         int n, int E) {
    const int gid = blockIdx.x * 256 + threadIdx.x;
    if (gid < n) off[gid] += bbase[blockIdx.x];
    if (gid == n) off[n] = E;
}

__global__ __launch_bounds__(256) void dinv_kernel(const int* __restrict__ cnt,
                                                   float* __restrict__ dinv, int n) {
    int i = blockIdx.x * 256 + threadIdx.x;
    if (i < n) {
        int c = cnt[i];
        dinv[i] = (c > 0) ? 1.0f / sqrtf((float)c) : 0.0f;
    }
}

__global__ __launch_bounds__(256) void scatter_kernel(const int* __restrict__ row,
                                                      const int* __restrict__ col,
                                                      const int* __restrict__ off,
                                                      const int* __restrict__ rank,
                                                      const float* __restrict__ dinv,
                                                      int2* __restrict__ recs, int E) {
    int e = blockIdx.x * 256 + threadIdx.x;
    if (e >= E) return;
    const int r = row[e], c = col[e];
    const int pos = off[c] + rank[e];
    recs[pos] = make_int2(r, __float_as_int(dinv[r] * dinv[c]));
}

// x -> fp16 copy
__global__ __launch_bounds__(256) void tohalf_kernel(const float* __restrict__ in,
                                                     __half* __restrict__ out, int n4) {
    int i = blockIdx.x * 256 + threadIdx.x;
    if (i >= n4) return;
    const float4 v = ((const float4*)in)[i];
    int2 o;
    o.x = f2i2(v.x, v.y);
    o.y = f2i2(v.z, v.w);
    ((int2*)out)[i] = o;
}

// ---------------- fused prop(fp16 gather) + GEMM ----------------
// DQ lanes per node (gather dim DIN = 4*DQ), 512-thread blocks, NPB = 512/DQ nodes.
// MODE 0: P = bias + cur@W0 + h1@W1 (W has both chunks contiguous); write h1 fp16.
// MODE 1: P += h@Wk; write h fp16.
// MODE 2: P += h@Wk; relu; write layer-out as fp16 ONLY (houth).
// MODE 3: P += h@Wk; relu; write P fp32 in place (final hidden layer).

template <int DQ, int MODE>
__global__ __launch_bounds__(512) void prop_gemm_h(
    const int* __restrict__ off, const int2* __restrict__ recs,
    const __half* __restrict__ gsrc,  // fp16 gather source (== cur for MODE 0)
    const float* __restrict__ W, const float* __restrict__ b,
    float* __restrict__ P, __half* __restrict__ houth, int nNodes) {
    constexpr int DIN = DQ * 4;
    constexpr int NPB = 512 / DQ;
    constexpr int INDIM = (MODE == 0) ? 2 * DIN : DIN;
    __shared__ __align__(16) float Ws[INDIM * 64];
    __shared__ __align__(16) float hs[NPB][INDIM + 4];
    __shared__ float bs[64];
    for (int i = threadIdx.x; i < INDIM * 64; i += 512) Ws[i] = W[i];
    if (MODE == 0 && threadIdx.x < 64) bs[threadIdx.x] = b[threadIdx.x];

    const int q = threadIdx.x & (DQ - 1);
    const int ln = threadIdx.x / DQ;
    const int n = blockIdx.x * NPB + ln;

    if (n < nNodes) {
        const int2* __restrict__ h2 = (const int2*)gsrc;
        float4 acc = make_float4(0.f, 0.f, 0.f, 0.f);
        int e = off[n];
        const int e1 = off[n + 1];
        for (; e + 4 <= e1; e += 4) {
            const int2 r0 = recs[e + 0];
            const int2 r1 = recs[e + 1];
            const int2 r2 = recs[e + 2];
            const int2 r3 = recs[e + 3];
            const int2 g0 = h2[r0.x * DQ + q];
            const int2 g1 = h2[r1.x * DQ + q];
            const int2 g2 = h2[r2.x * DQ + q];
            const int2 g3 = h2[r3.x * DQ + q];
            const float w0 = __int_as_float(r0.y), w1 = __int_as_float(r1.y);
            const float w2 = __int_as_float(r2.y), w3 = __int_as_float(r3.y);
            const float2 a0 = i2f2(g0.x), a1 = i2f2(g0.y);
            const float2 b0 = i2f2(g1.x), b1 = i2f2(g1.y);
            const float2 c0 = i2f2(g2.x), c1 = i2f2(g2.y);
            const float2 d0 = i2f2(g3.x), d1 = i2f2(g3.y);
            acc.x += w0 * a0.x + w1 * b0.x + w2 * c0.x + w3 * d0.x;
            acc.y += w0 * a0.y + w1 * b0.y + w2 * c0.y + w3 * d0.y;
            acc.z += w0 * a1.x + w1 * b1.x + w2 * c1.x + w3 * d1.x;
            acc.w += w0 * a1.y + w1 * b1.y + w2 * c1.y + w3 * d1.y;
        }
        for (; e < e1; ++e) {
            const int2 r = recs[e];
            const int2 g = h2[r.x * DQ + q];
            const float ww = __int_as_float(r.y);
            const float2 lo = i2f2(g.x), hi = i2f2(g.y);
            acc.x += ww * lo.x;
            acc.y += ww * lo.y;
            acc.z += ww * hi.x;
            acc.w += ww * hi.y;
        }
        if (MODE == 0) {
            // own row of cur for the k=0 term
            const int2 rc = h2[n * DQ + q];
            const float2 clo = i2f2(rc.x), chi = i2f2(rc.y);
            hs[ln][q * 4 + 0] = clo.x;
            hs[ln][q * 4 + 1] = clo.y;
            hs[ln][q * 4 + 2] = chi.x;
            hs[ln][q * 4 + 3] = chi.y;
            *(float4*)&hs[ln][DIN + q * 4] = acc;
        } else {
            *(float4*)&hs[ln][q * 4] = acc;
        }
        if (MODE == 0 || MODE == 1) {
            int2 o;
            o.x = f2i2(acc.x, acc.y);
            o.y = f2i2(acc.z, acc.w);
            ((int2*)houth)[n * DQ + q] = o;
        }
    }
    __syncthreads();

    if (n >= nNodes) return;
    const float4* W4 = (const float4*)Ws;
    if (DQ == 16) {
        float4* o = (float4*)(P + (size_t)n * 64) + q;
        float4 a;
        if (MODE == 0)
            a = make_float4(bs[q * 4 + 0], bs[q * 4 + 1], bs[q * 4 + 2], bs[q * 4 + 3]);
        else
            a = *o;
        const float* hr = hs[ln];
#pragma unroll
        for (int i = 0; i < INDIM; i += 4) {
            const float4 hv = *(const float4*)(hr + i);
            const float4 w0 = W4[(i + 0) * 16 + q];
            const float4 w1 = W4[(i + 1) * 16 + q];
            const float4 w2 = W4[(i + 2) * 16 + q];
            const float4 w3 = W4[(i + 3) * 16 + q];
            a.x += hv.x * w0.x + hv.y * w1.x + hv.z * w2.x + hv.w * w3.x;
            a.y += hv.x * w0.y + hv.y * w1.y + hv.z * w2.y + hv.w * w3.y;
            a.z += hv.x * w0.z + hv.y * w1.z + hv.z * w2.z + hv.w * w3.z;
            a.w += hv.x * w0.w + hv.y * w1.w + hv.z * w2.w + hv.w * w3.w;
        }
        if (MODE == 2 || MODE == 3) {
            a.x = fmaxf(a.x, 0.f);
            a.y = fmaxf(a.y, 0.f);
            a.z = fmaxf(a.z, 0.f);
            a.w = fmaxf(a.w, 0.f);
        }
        if (MODE == 2) {
            int2 oh;
            oh.x = f2i2(a.x, a.y);
            oh.y = f2i2(a.z, a.w);
            ((int2*)houth)[n * 16 + q] = oh;
        } else {
            *o = a;
        }
    } else {
        // DQ==4: thread covers 16 output cols at q*16
        float4* o = (float4*)(P + (size_t)n * 64) + q * 4;
        float4 a0, a1, a2, a3;
        if (MODE == 0) {
            a0 = *(const float4*)&bs[q * 16 + 0];
            a1 = *(const float4*)&bs[q * 16 + 4];
            a2 = *(const float4*)&bs[q * 16 + 8];
            a3 = *(const float4*)&bs[q * 16 + 12];
        } else {
            a0 = o[0];
            a1 = o[1];
            a2 = o[2];
            a3 = o[3];
        }
        const float* hr = hs[ln];
#pragma unroll
        for (int i = 0; i < INDIM; ++i) {
            const float hv = hr[i];
            const float4 w0 = W4[i * 16 + q * 4 + 0];
            const float4 w1 = W4[i * 16 + q * 4 + 1];
            const float4 w2 = W4[i * 16 + q * 4 + 2];
            const float4 w3 = W4[i * 16 + q * 4 + 3];
            a0.x += hv * w0.x; a0.y += hv * w0.y; a0.z += hv * w0.z; a0.w += hv * w0.w;
            a1.x += hv * w1.x; a1.y += hv * w1.y; a1.z += hv * w1.z; a1.w += hv * w1.w;
            a2.x += hv * w2.x; a2.y += hv * w2.y; a2.z += hv * w2.z; a2.w += hv * w2.w;
            a3.x += hv * w3.x; a3.y += hv * w3.y; a3.z += hv * w3.z; a3.w += hv * w3.w;
        }
        if (MODE == 2 || MODE == 3) {
            a0.x = fmaxf(a0.x, 0.f); a0.y = fmaxf(a0.y, 0.f); a0.z = fmaxf(a0.z, 0.f); a0.w = fmaxf(a0.w, 0.f);
            a1.x = fmaxf(a1.x, 0.f); a1.y = fmaxf(a1.y, 0.f); a1.z = fmaxf(a1.z, 0.f); a1.w = fmaxf(a1.w, 0.f);
            a2.x = fmaxf(a2.x, 0.f); a2.y = fmaxf(a2.y, 0.f); a2.z = fmaxf(a2.z, 0.f); a2.w = fmaxf(a2.w, 0.f);
            a3.x = fmaxf(a3.x, 0.f); a3.y = fmaxf(a3.y, 0.f); a3.z = fmaxf(a3.z, 0.f); a3.w = fmaxf(a3.w, 0.f);
        }
        if (MODE == 2) {
            int2* oh = (int2*)houth + (size_t)n * 16 + q * 4;
            oh[0] = make_int2(f2i2(a0.x, a0.y), f2i2(a0.z, a0.w));
            oh[1] = make_int2(f2i2(a1.x, a1.y), f2i2(a1.z, a1.w));
            oh[2] = make_int2(f2i2(a2.x, a2.y), f2i2(a2.z, a2.w));
            oh[3] = make_int2(f2i2(a3.x, a3.y), f2i2(a3.z, a3.w));
        } else {
            o[0] = a0;
            o[1] = a1;
            o[2] = a2;
            o[3] = a3;
        }
    }
}

// ---------------- layer 4: all four 4-dim projections in one pass ----------------

__global__ __launch_bounds__(256) void proj4_kernel(const float* __restrict__ h,
                                                    const float* __restrict__ W,
                                                    float* __restrict__ P0,
                                                    float* __restrict__ P1,
                                                    float* __restrict__ P2,
                                                    float* __restrict__ P3, int nNodes) {
    __shared__ float Ws[4 * 64 * 4];
    for (int i = threadIdx.x; i < 1024; i += 256) Ws[i] = W[i];
    __syncthreads();
    const int k = threadIdx.x & 3;
    const int n = blockIdx.x * 64 + (threadIdx.x >> 2);
    if (n >= nNodes) return;
    const float4* __restrict__ h4 = (const float4*)(h + (size_t)n * 64);
    const float4* W4 = (const float4*)(Ws + k * 256);
    float4 acc = make_float4(0.f, 0.f, 0.f, 0.f);
#pragma unroll
    for (int i4 = 0; i4 < 16; ++i4) {
        const float4 hv = h4[i4];
        const float4 w0 = W4[i4 * 4 + 0];
        const float4 w1 = W4[i4 * 4 + 1];
        const float4 w2 = W4[i4 * 4 + 2];
        const float4 w3 = W4[i4 * 4 + 3];
        acc.x += hv.x * w0.x + hv.y * w1.x + hv.z * w2.x + hv.w * w3.x;
        acc.y += hv.x * w0.y + hv.y * w1.y + hv.z * w2.y + hv.w * w3.y;
        acc.z += hv.x * w0.z + hv.y * w1.z + hv.z * w2.z + hv.w * w3.z;
        acc.w += hv.x * w0.w + hv.y * w1.w + hv.z * w2.w + hv.w * w3.w;
    }
    float4* dst = (k == 0) ? (float4*)P0 : (k == 1) ? (float4*)P1 : (k == 2) ? (float4*)P2
                                                                             : (float4*)P3;
    dst[n] = acc;
}

// Horner step on 4-dim signals: out[n] = P[n] (+bias) + sum_e norm_e * U[src_e]
template <bool FINAL>
__global__ __launch_bounds__(256) void prop1_add_kernel(const int* __restrict__ off,
                                                        const int2* __restrict__ recs,
                                                        const float* __restrict__ Uin,
                                                        const float* __restrict__ P,
                                                        const float* __restrict__ b,
                                                        float* __restrict__ out, int nNodes) {
    const int n = blockIdx.x * 256 + threadIdx.x;
    if (n >= nNodes) return;
    const float4* __restrict__ u4 = (const float4*)Uin;
    float4 acc = ((const float4*)P)[n];
    if (FINAL) {
        const float4 bv = *(const float4*)b;
        acc.x += bv.x;
        acc.y += bv.y;
        acc.z += bv.z;
        acc.w += bv.w;
    }
    int e = off[n];
    const int e1 = off[n + 1];
    for (; e + 4 <= e1; e += 4) {
        const int2 r0 = recs[e + 0];
        const int2 r1 = recs[e + 1];
        const int2 r2 = recs[e + 2];
        const int2 r3 = recs[e + 3];
        const float4 a = u4[r0.x], bb = u4[r1.x], c = u4[r2.x], d = u4[r3.x];
        const float w0 = __int_as_float(r0.y), w1 = __int_as_float(r1.y);
        const float w2 = __int_as_float(r2.y), w3 = __int_as_float(r3.y);
        acc.x += w0 * a.x + w1 * bb.x + w2 * c.x + w3 * d.x;
        acc.y += w0 * a.y + w1 * bb.y + w2 * c.y + w3 * d.y;
        acc.z += w0 * a.z + w1 * bb.z + w2 * c.z + w3 * d.z;
        acc.w += w0 * a.w + w1 * bb.w + w2 * c.w + w3 * d.w;
    }
    for (; e < e1; ++e) {
        const int2 r = recs[e];
        const float ww = __int_as_float(r.y);
        const float4 hv = u4[r.x];
        acc.x += ww * hv.x;
        acc.y += ww * hv.y;
        acc.z += ww * hv.z;
        acc.w += ww * hv.w;
    }
    ((float4*)out)[n] = acc;
}

// ---------------- host ----------------

extern "C" void kernel_launch(void* const* d_in, const int* in_sizes, int n_in,
                              void* d_out, int out_size, void* d_ws, size_t ws_size,
                              hipStream_t stream) {
    const float* x = (const float*)d_in[0];
    const int* ei = (const int*)d_in[1];
    const float* W[5] = {(const float*)d_in[2], (const float*)d_in[4], (const float*)d_in[6],
                         (const float*)d_in[8], (const float*)d_in[10]};
    const float* bb[5] = {(const float*)d_in[3], (const float*)d_in[5], (const float*)d_in[7],
                          (const float*)d_in[9], (const float*)d_in[11]};
    const int E = in_sizes[1] / 2;   // 800000
    const int N = in_sizes[0] / 16;  // 50000
    float* outp = (float*)d_out;

    char* p = (char*)d_ws;
    auto alloc = [&](size_t bytes) {
        char* r = p;
        p += (bytes + 255) & ~size_t(255);
        return r;
    };
    const int nb = (N + 255) / 256;
    int* cnt = (int*)alloc((size_t)N * 4);
    int* off = (int*)alloc((size_t)(N + 1) * 4);
    float* dinv = (float*)alloc((size_t)N * 4);
    int* bsum = (int*)alloc((size_t)nb * 4);
    int* bbase = (int*)alloc((size_t)nb * 4);
    int* rank = (int*)alloc((size_t)E * 4);
    int2* recs = (int2*)alloc((size_t)E * 8);
    float* P = (float*)alloc((size_t)N * 64 * 4);    // fp32 partial / final hidden
    __half* xh = (__half*)alloc((size_t)N * 16 * 2);
    __half* hb1 = (__half*)alloc((size_t)N * 64 * 2);
    __half* hb2 = (__half*)alloc((size_t)N * 64 * 2);
    __half* Oh = (__half*)alloc((size_t)N * 64 * 2);
    __half* Ah = (__half*)alloc((size_t)N * 64 * 2);
    float* P0 = (float*)alloc((size_t)N * 4 * 4);
    float* P1 = (float*)alloc((size_t)N * 4 * 4);
    float* P2 = (float*)alloc((size_t)N * 4 * 4);
    float* P3 = (float*)alloc((size_t)N * 4 * 4);
    float* Ua = (float*)alloc((size_t)N * 4 * 4);
    float* Ub = (float*)alloc((size_t)N * 4 * 4);

    hipMemsetAsync(cnt, 0, (size_t)N * 4, stream);
    const int eb = (E + 255) / 256;
    count_rank_kernel<<<eb, 256, 0, stream>>>(ei + E, cnt, rank, E);
    scan_block_kernel<<<nb, 256, 0, stream>>>(cnt, off, bsum, N);
    scan_bsum_kernel<<<1, 256, 0, stream>>>(bsum, bbase, nb);
    scan_apply_kernel<<<nb, 256, 0, stream>>>(off, bbase, N, E);
    dinv_kernel<<<nb, 256, 0, stream>>>(cnt, dinv, N);
    scatter_kernel<<<eb, 256, 0, stream>>>(ei, ei + E, off, rank, dinv, recs, E);
    tohalf_kernel<<<(N * 4 + 255) / 256, 256, 0, stream>>>(x, xh, N * 4);

    const int g16 = (N + 31) / 32;    // DQ=16: 32 nodes/block (512 thr)
    const int g4b = (N + 127) / 128;  // DQ=4: 128 nodes/block (512 thr)
    const int gq = (N + 63) / 64;
    const int p1 = (N + 255) / 256;

    // Layer 0 (DIN=16): P = b0 + x@W00 + g1@W01; += g2@W02; += g3@W03 -> relu -> Oh
    prop_gemm_h<4, 0><<<g4b, 512, 0, stream>>>(off, recs, xh, W[0], bb[0], P,
                                               (__half*)hb1, N);
    prop_gemm_h<4, 1><<<g4b, 512, 0, stream>>>(off, recs, (__half*)hb1, W[0] + 2 * 1024,
                                               nullptr, P, (__half*)hb2, N);
    prop_gemm_h<4, 2><<<g4b, 512, 0, stream>>>(off, recs, (__half*)hb2, W[0] + 3 * 1024,
                                               nullptr, P, Oh, N);

    // Layers 1-3 (DIN=64): curh ping-pongs Oh/Ah; layer 3 ends with fp32 P (MODE 3)
    const __half* curh = Oh;
    __half* nxth = Ah;
    for (int l = 1; l <= 3; ++l) {
        const float* Wl = W[l];
        prop_gemm_h<16, 0><<<g16, 512, 0, stream>>>(off, recs, curh, Wl, bb[l], P, hb1, N);
        prop_gemm_h<16, 1><<<g16, 512, 0, stream>>>(off, recs, hb1, Wl + 2 * 4096, nullptr,
                                                    P, hb2, N);
        if (l < 3) {
            prop_gemm_h<16, 2><<<g16, 512, 0, stream>>>(off, recs, hb2, Wl + 3 * 4096,
                                                        nullptr, P, nxth, N);
            const __half* t = curh;
            curh = nxth;
            nxth = (__half*)t;
        } else {
            prop_gemm_h<16, 3><<<g16, 512, 0, stream>>>(off, recs, hb2, Wl + 3 * 4096,
                                                        nullptr, P, nullptr, N);
        }
    }

    // Layer 4: P_k = P@W4_k (one read of P), then Horner on 4-dim signals
    proj4_kernel<<<gq, 256, 0, stream>>>(P, W[4], P0, P1, P2, P3, N);
    prop1_add_kernel<false><<<p1, 256, 0, stream>>>(off, recs, P3, P2, nullptr, Ua, N);
    prop1_add_kernel<false><<<p1, 256, 0, stream>>>(off, recs, Ua, P1, nullptr, Ub, N);
    prop1_add_kernel<true><<<p1, 256, 0, stream>>>(off, recs, Ub, P0, bb[4], outp, N);
}

// Round 6
// 433.387 us; speedup vs baseline: 1.4884x; 1.0402x over previous
//
#include <hip/hip_runtime.h>
#include <hip/hip_fp16.h>

// ---------------- fp16 helpers ----------------
union H2I { int i; __half2 h; };
static __device__ inline float2 i2f2(int v) {
    H2I u; u.i = v; return __half22float2(u.h);
}
static __device__ inline int f2i2(float a, float b) {
    H2I u; u.h = __floats2half2_rn(a, b); return u.i;
}

struct F8 { float2 a, b, c, d; };
static __device__ inline void fma8(F8& s, int4 g, float w) {
    float2 t;
    t = i2f2(g.x); s.a.x += w * t.x; s.a.y += w * t.y;
    t = i2f2(g.y); s.b.x += w * t.x; s.b.y += w * t.y;
    t = i2f2(g.z); s.c.x += w * t.x; s.c.y += w * t.y;
    t = i2f2(g.w); s.d.x += w * t.x; s.d.y += w * t.y;
}

// ---------------- CSR build ----------------

__global__ __launch_bounds__(256) void count_rank_kernel(const int* __restrict__ col,
                                                         int* __restrict__ cnt,
                                                         int* __restrict__ rank, int E) {
    int e = blockIdx.x * 256 + threadIdx.x;
    if (e < E) rank[e] = atomicAdd(&cnt[col[e]], 1);
}

__global__ __launch_bounds__(256) void scan_block_kernel(const int* __restrict__ cnt,
                                                         int* __restrict__ off,
                                                         int* __restrict__ bsum, int n) {
    const int gid = blockIdx.x * 256 + threadIdx.x;
    const int v = (gid < n) ? cnt[gid] : 0;
    const int lane = threadIdx.x & 63, w = threadIdx.x >> 6;
    int x = v;
#pragma unroll
    for (int d = 1; d < 64; d <<= 1) {
        int t = __shfl_up(x, d);
        if (lane >= d) x += t;
    }
    __shared__ int wt[4];
    if (lane == 63) wt[w] = x;
    __syncthreads();
    int base = 0;
#pragma unroll
    for (int i = 0; i < 3; ++i)
        if (i < w) base += wt[i];
    const int incl = base + x;
    if (gid < n) off[gid] = incl - v;
    if (threadIdx.x == 255) bsum[blockIdx.x] = incl;
}

__global__ __launch_bounds__(256) void scan_bsum_kernel(const int* __restrict__ bsum,
                                                        int* __restrict__ bbase, int nb) {
    const int tid = threadIdx.x;
    const int v = (tid < nb) ? bsum[tid] : 0;
    const int lane = tid & 63, w = tid >> 6;
    int x = v;
#pragma unroll
    for (int d = 1; d < 64; d <<= 1) {
        int t = __shfl_up(x, d);
        if (lane >= d) x += t;
    }
    __shared__ int wt[4];
    if (lane == 63) wt[w] = x;
    __syncthreads();
    int base = 0;
#pragma unroll
    for (int i = 0; i < 3; ++i)
        if (i < w) base += wt[i];
    if (tid < nb) bbase[tid] = base + x - v;
}

__global__ __launch_bounds__(256) void scan_apply_kernel(int* __restrict__ off,
                                                         const int* __restrict__ bbase,
                                                         int n, int E) {
    const int gid = blockIdx.x * 256 + threadIdx.x;
    if (gid < n) off[gid] += bbase[blockIdx.x];
    if (gid == n) off[n] = E;
}

__global__ __launch_bounds__(256) void dinv_kernel(const int* __restrict__ cnt,
                                                   float* __restrict__ dinv, int n) {
    int i = blockIdx.x * 256 + threadIdx.x;
    if (i < n) {
        int c = cnt[i];
        dinv[i] = (c > 0) ? 1.0f / sqrtf((float)c) : 0.0f;
    }
}

__global__ __launch_bounds__(256) void scatter_kernel(const int* __restrict__ row,
                                                      const int* __restrict__ col,
                                                      const int* __restrict__ off,
                                                      const int* __restrict__ rank,
                                                      const float* __restrict__ dinv,
                                                      int2* __restrict__ recs, int E) {
    int e = blockIdx.x * 256 + threadIdx.x;
    if (e >= E) return;
    const int r = row[e], c = col[e];
    const int pos = off[c] + rank[e];
    recs[pos] = make_int2(r, __float_as_int(dinv[r] * dinv[c]));
}

// x -> fp16 copy
__global__ __launch_bounds__(256) void tohalf_kernel(const float* __restrict__ in,
                                                     __half* __restrict__ out, int n4) {
    int i = blockIdx.x * 256 + threadIdx.x;
    if (i >= n4) return;
    const float4 v = ((const float4*)in)[i];
    ((int2*)out)[i] = make_int2(f2i2(v.x, v.y), f2i2(v.z, v.w));
}

// ---------------- pure fp16 hop: hout = A_norm * hin ----------------
// DQ lanes/node, each owns one int4 (8 halfs) of the row. No LDS -> max occupancy.

template <int DQ>
__global__ __launch_bounds__(256) void gatherh_kernel(const int* __restrict__ off,
                                                      const int2* __restrict__ recs,
                                                      const __half* __restrict__ hin,
                                                      __half* __restrict__ hout, int nNodes) {
    const int t = blockIdx.x * 256 + threadIdx.x;
    const int n = t / DQ;
    const int q = t & (DQ - 1);
    if (n >= nNodes) return;
    const int4* __restrict__ h4 = (const int4*)hin;
    F8 s = {};
    int e = off[n];
    const int e1 = off[n + 1];
    for (; e + 4 <= e1; e += 4) {
        const int2 r0 = recs[e + 0];
        const int2 r1 = recs[e + 1];
        const int2 r2 = recs[e + 2];
        const int2 r3 = recs[e + 3];
        const int4 g0 = h4[r0.x * DQ + q];
        const int4 g1 = h4[r1.x * DQ + q];
        const int4 g2 = h4[r2.x * DQ + q];
        const int4 g3 = h4[r3.x * DQ + q];
        fma8(s, g0, __int_as_float(r0.y));
        fma8(s, g1, __int_as_float(r1.y));
        fma8(s, g2, __int_as_float(r2.y));
        fma8(s, g3, __int_as_float(r3.y));
    }
    for (; e < e1; ++e) {
        const int2 r = recs[e];
        fma8(s, h4[r.x * DQ + q], __int_as_float(r.y));
    }
    int4 o;
    o.x = f2i2(s.a.x, s.a.y);
    o.y = f2i2(s.b.x, s.b.y);
    o.z = f2i2(s.c.x, s.c.y);
    o.w = f2i2(s.d.x, s.d.y);
    ((int4*)hout)[n * DQ + q] = o;
}

// ---------------- concat GEMM: out = relu([s0|s1|s2|s3] @ W + b) ----------------
// W flat [4][DINEACH][64] (the raw layer weight). fp16 W in LDS, fp32 accumulate.
// 16 lanes/node; lane q computes output cols 4q..4q+3.

template <int DINEACH>
__global__ __launch_bounds__(256) void gemmcat_kernel(
    const __half* __restrict__ s0, const __half* __restrict__ s1,
    const __half* __restrict__ s2, const __half* __restrict__ s3,
    const float* __restrict__ W, const float* __restrict__ b,
    __half* __restrict__ out, int nNodes) {
    constexpr int INDIM = 4 * DINEACH;
    __shared__ __half2 Ws[INDIM * 32];
    __shared__ float bs[64];
    for (int i = threadIdx.x; i < INDIM * 32; i += 256) {
        const float2 wv = ((const float2*)W)[i];
        Ws[i] = __floats2half2_rn(wv.x, wv.y);
    }
    if (threadIdx.x < 64) bs[threadIdx.x] = b[threadIdx.x];
    __syncthreads();
    const int q = threadIdx.x & 15;
    const int n = blockIdx.x * 16 + (threadIdx.x >> 4);
    if (n >= nNodes) return;
    float4 a = make_float4(bs[q * 4 + 0], bs[q * 4 + 1], bs[q * 4 + 2], bs[q * 4 + 3]);
#pragma unroll
    for (int k = 0; k < 4; ++k) {
        const __half* sk = (k == 0) ? s0 : (k == 1) ? s1 : (k == 2) ? s2 : s3;
        const int4* __restrict__ hk = (const int4*)sk + (size_t)n * (DINEACH / 8);
#pragma unroll
        for (int i8 = 0; i8 < DINEACH / 8; ++i8) {
            const int4 g = hk[i8];
            const float2 f0 = i2f2(g.x), f1 = i2f2(g.y), f2v = i2f2(g.z), f3 = i2f2(g.w);
            const float hv[8] = {f0.x, f0.y, f1.x, f1.y, f2v.x, f2v.y, f3.x, f3.y};
            const int row = k * DINEACH + i8 * 8;
#pragma unroll
            for (int j = 0; j < 8; ++j) {
                const float2 wA = __half22float2(Ws[(row + j) * 32 + q * 2 + 0]);
                const float2 wB = __half22float2(Ws[(row + j) * 32 + q * 2 + 1]);
                a.x += hv[j] * wA.x;
                a.y += hv[j] * wA.y;
                a.z += hv[j] * wB.x;
                a.w += hv[j] * wB.y;
            }
        }
    }
    a.x = fmaxf(a.x, 0.f);
    a.y = fmaxf(a.y, 0.f);
    a.z = fmaxf(a.z, 0.f);
    a.w = fmaxf(a.w, 0.f);
    ((int2*)out)[n * 16 + q] = make_int2(f2i2(a.x, a.y), f2i2(a.z, a.w));
}

// ---------------- layer 4: four 4-dim projections from fp16 h ----------------

__global__ __launch_bounds__(256) void proj4h_kernel(const __half* __restrict__ h,
                                                     const float* __restrict__ W,
                                                     float* __restrict__ P0,
                                                     float* __restrict__ P1,
                                                     float* __restrict__ P2,
                                                     float* __restrict__ P3, int nNodes) {
    __shared__ float Ws[4 * 64 * 4];
    for (int i = threadIdx.x; i < 1024; i += 256) Ws[i] = W[i];
    __syncthreads();
    const int k = threadIdx.x & 3;
    const int n = blockIdx.x * 64 + (threadIdx.x >> 2);
    if (n >= nNodes) return;
    const int4* __restrict__ h8 = (const int4*)h + (size_t)n * 8;
    const float4* W4 = (const float4*)(Ws + k * 256);  // 64 rows x 4 cols
    float4 acc = make_float4(0.f, 0.f, 0.f, 0.f);
#pragma unroll
    for (int i8 = 0; i8 < 8; ++i8) {
        const int4 g = h8[i8];
        const float2 f0 = i2f2(g.x), f1 = i2f2(g.y), f2v = i2f2(g.z), f3 = i2f2(g.w);
        const float hv[8] = {f0.x, f0.y, f1.x, f1.y, f2v.x, f2v.y, f3.x, f3.y};
#pragma unroll
        for (int j = 0; j < 8; ++j) {
            const float4 wr = W4[i8 * 8 + j];
            acc.x += hv[j] * wr.x;
            acc.y += hv[j] * wr.y;
            acc.z += hv[j] * wr.z;
            acc.w += hv[j] * wr.w;
        }
    }
    float4* dst = (k == 0) ? (float4*)P0 : (k == 1) ? (float4*)P1 : (k == 2) ? (float4*)P2
                                                                             : (float4*)P3;
    dst[n] = acc;
}

// Horner step on 4-dim fp32 signals: out[n] = P[n] (+bias) + sum_e norm_e * U[src_e]
template <bool FINAL>
__global__ __launch_bounds__(256) void prop1_add_kernel(const int* __restrict__ off,
                                                        const int2* __restrict__ recs,
                                                        const float* __restrict__ Uin,
                                                        const float* __restrict__ P,
                                                        const float* __restrict__ b,
                                                        float* __restrict__ out, int nNodes) {
    const int n = blockIdx.x * 256 + threadIdx.x;
    if (n >= nNodes) return;
    const float4* __restrict__ u4 = (const float4*)Uin;
    float4 acc = ((const float4*)P)[n];
    if (FINAL) {
        const float4 bv = *(const float4*)b;
        acc.x += bv.x;
        acc.y += bv.y;
        acc.z += bv.z;
        acc.w += bv.w;
    }
    int e = off[n];
    const int e1 = off[n + 1];
    for (; e + 4 <= e1; e += 4) {
        const int2 r0 = recs[e + 0];
        const int2 r1 = recs[e + 1];
        const int2 r2 = recs[e + 2];
        const int2 r3 = recs[e + 3];
        const float4 a = u4[r0.x], bb = u4[r1.x], c = u4[r2.x], d = u4[r3.x];
        const float w0 = __int_as_float(r0.y), w1 = __int_as_float(r1.y);
        const float w2 = __int_as_float(r2.y), w3 = __int_as_float(r3.y);
        acc.x += w0 * a.x + w1 * bb.x + w2 * c.x + w3 * d.x;
        acc.y += w0 * a.y + w1 * bb.y + w2 * c.y + w3 * d.y;
        acc.z += w0 * a.z + w1 * bb.z + w2 * c.z + w3 * d.z;
        acc.w += w0 * a.w + w1 * bb.w + w2 * c.w + w3 * d.w;
    }
    for (; e < e1; ++e) {
        const int2 r = recs[e];
        const float ww = __int_as_float(r.y);
        const float4 hv = u4[r.x];
        acc.x += ww * hv.x;
        acc.y += ww * hv.y;
        acc.z += ww * hv.z;
        acc.w += ww * hv.w;
    }
    ((float4*)out)[n] = acc;
}

// ---------------- host ----------------

extern "C" void kernel_launch(void* const* d_in, const int* in_sizes, int n_in,
                              void* d_out, int out_size, void* d_ws, size_t ws_size,
                              hipStream_t stream) {
    const float* x = (const float*)d_in[0];
    const int* ei = (const int*)d_in[1];
    const float* W[5] = {(const float*)d_in[2], (const float*)d_in[4], (const float*)d_in[6],
                         (const float*)d_in[8], (const float*)d_in[10]};
    const float* bb[5] = {(const float*)d_in[3], (const float*)d_in[5], (const float*)d_in[7],
                          (const float*)d_in[9], (const float*)d_in[11]};
    const int E = in_sizes[1] / 2;   // 800000
    const int N = in_sizes[0] / 16;  // 50000
    float* outp = (float*)d_out;

    char* p = (char*)d_ws;
    auto alloc = [&](size_t bytes) {
        char* r = p;
        p += (bytes + 255) & ~size_t(255);
        return r;
    };
    const int nb = (N + 255) / 256;
    int* cnt = (int*)alloc((size_t)N * 4);
    int* off = (int*)alloc((size_t)(N + 1) * 4);
    float* dinv = (float*)alloc((size_t)N * 4);
    int* bsum = (int*)alloc((size_t)nb * 4);
    int* bbase = (int*)alloc((size_t)nb * 4);
    int* rank = (int*)alloc((size_t)E * 4);
    int2* recs = (int2*)alloc((size_t)E * 8);
    __half* xh = (__half*)alloc((size_t)N * 16 * 2);
    __half* x1 = (__half*)alloc((size_t)N * 16 * 2);
    __half* x2 = (__half*)alloc((size_t)N * 16 * 2);
    __half* x3 = (__half*)alloc((size_t)N * 16 * 2);
    __half* curA = (__half*)alloc((size_t)N * 64 * 2);
    __half* curB = (__half*)alloc((size_t)N * 64 * 2);
    __half* h1 = (__half*)alloc((size_t)N * 64 * 2);
    __half* h2 = (__half*)alloc((size_t)N * 64 * 2);
    __half* h3 = (__half*)alloc((size_t)N * 64 * 2);
    float* P0 = (float*)alloc((size_t)N * 4 * 4);
    float* P1 = (float*)alloc((size_t)N * 4 * 4);
    float* P2 = (float*)alloc((size_t)N * 4 * 4);
    float* P3 = (float*)alloc((size_t)N * 4 * 4);
    float* Ua = (float*)alloc((size_t)N * 4 * 4);
    float* Ub = (float*)alloc((size_t)N * 4 * 4);

    hipMemsetAsync(cnt, 0, (size_t)N * 4, stream);
    const int eb = (E + 255) / 256;
    count_rank_kernel<<<eb, 256, 0, stream>>>(ei + E, cnt, rank, E);
    scan_block_kernel<<<nb, 256, 0, stream>>>(cnt, off, bsum, N);
    scan_bsum_kernel<<<1, 256, 0, stream>>>(bsum, bbase, nb);
    scan_apply_kernel<<<nb, 256, 0, stream>>>(off, bbase, N, E);
    dinv_kernel<<<nb, 256, 0, stream>>>(cnt, dinv, N);
    scatter_kernel<<<eb, 256, 0, stream>>>(ei, ei + E, off, rank, dinv, recs, E);
    tohalf_kernel<<<(N * 4 + 255) / 256, 256, 0, stream>>>(x, xh, N * 4);

    const int gh2 = (N * 2 + 255) / 256;   // DQ=2 hop grid
    const int gh8 = (N * 8 + 255) / 256;   // DQ=8 hop grid
    const int gg = (N + 15) / 16;          // gemmcat grid
    const int gq = (N + 63) / 64;
    const int p1 = (N + 255) / 256;

    // Layer 0: hops on 16-dim x, one concat GEMM [x|x1|x2|x3](64) -> 64
    gatherh_kernel<2><<<gh2, 256, 0, stream>>>(off, recs, xh, x1, N);
    gatherh_kernel<2><<<gh2, 256, 0, stream>>>(off, recs, x1, x2, N);
    gatherh_kernel<2><<<gh2, 256, 0, stream>>>(off, recs, x2, x3, N);
    gemmcat_kernel<16><<<gg, 256, 0, stream>>>(xh, x1, x2, x3, W[0], bb[0], curA, N);

    // Layers 1-3: three 64-dim hops + one concat GEMM [h|h1|h2|h3](256) -> 64
    __half* cur = curA;
    __half* nxt = curB;
    for (int l = 1; l <= 3; ++l) {
        gatherh_kernel<8><<<gh8, 256, 0, stream>>>(off, recs, cur, h1, N);
        gatherh_kernel<8><<<gh8, 256, 0, stream>>>(off, recs, h1, h2, N);
        gatherh_kernel<8><<<gh8, 256, 0, stream>>>(off, recs, h2, h3, N);
        gemmcat_kernel<64><<<gg, 256, 0, stream>>>(cur, h1, h2, h3, W[l], bb[l], nxt, N);
        __half* t = cur;
        cur = nxt;
        nxt = t;
    }

    // Layer 4: P_k = cur@W4_k (one fp16 read of cur), Horner on 4-dim fp32 signals
    proj4h_kernel<<<gq, 256, 0, stream>>>(cur, W[4], P0, P1, P2, P3, N);
    prop1_add_kernel<false><<<p1, 256, 0, stream>>>(off, recs, P3, P2, nullptr, Ua, N);
    prop1_add_kernel<false><<<p1, 256, 0, stream>>>(off, recs, Ua, P1, nullptr, Ub, N);
    prop1_add_kernel<true><<<p1, 256, 0, stream>>>(off, recs, Ub, P0, bb[4], outp, N);
}

// Round 7
// 337.682 us; speedup vs baseline: 1.9103x; 1.2834x over previous
//
#include <hip/hip_runtime.h>
#include <hip/hip_fp16.h>

typedef _Float16 f16x8 __attribute__((ext_vector_type(8)));
typedef float f32x4 __attribute__((ext_vector_type(4)));

// ---------------- fp16 helpers ----------------
union H2I { int i; __half2 h; };
static __device__ inline float2 i2f2(int v) {
    H2I u; u.i = v; return __half22float2(u.h);
}
static __device__ inline int f2i2(float a, float b) {
    H2I u; u.h = __floats2half2_rn(a, b); return u.i;
}

struct F8 { float2 a, b, c, d; };
static __device__ inline void fma8(F8& s, int4 g, float w) {
    float2 t;
    t = i2f2(g.x); s.a.x += w * t.x; s.a.y += w * t.y;
    t = i2f2(g.y); s.b.x += w * t.x; s.b.y += w * t.y;
    t = i2f2(g.z); s.c.x += w * t.x; s.c.y += w * t.y;
    t = i2f2(g.w); s.d.x += w * t.x; s.d.y += w * t.y;
}

// ---------------- CSR build ----------------

__global__ __launch_bounds__(256) void count_rank_kernel(const int* __restrict__ col,
                                                         int* __restrict__ cnt,
                                                         int* __restrict__ rank, int E) {
    int e = blockIdx.x * 256 + threadIdx.x;
    if (e < E) rank[e] = atomicAdd(&cnt[col[e]], 1);
}

__global__ __launch_bounds__(256) void scan_block_kernel(const int* __restrict__ cnt,
                                                         int* __restrict__ off,
                                                         int* __restrict__ bsum, int n) {
    const int gid = blockIdx.x * 256 + threadIdx.x;
    const int v = (gid < n) ? cnt[gid] : 0;
    const int lane = threadIdx.x & 63, w = threadIdx.x >> 6;
    int x = v;
#pragma unroll
    for (int d = 1; d < 64; d <<= 1) {
        int t = __shfl_up(x, d);
        if (lane >= d) x += t;
    }
    __shared__ int wt[4];
    if (lane == 63) wt[w] = x;
    __syncthreads();
    int base = 0;
#pragma unroll
    for (int i = 0; i < 3; ++i)
        if (i < w) base += wt[i];
    const int incl = base + x;
    if (gid < n) off[gid] = incl - v;
    if (threadIdx.x == 255) bsum[blockIdx.x] = incl;
}

__global__ __launch_bounds__(256) void scan_bsum_kernel(const int* __restrict__ bsum,
                                                        int* __restrict__ bbase, int nb) {
    const int tid = threadIdx.x;
    const int v = (tid < nb) ? bsum[tid] : 0;
    const int lane = tid & 63, w = tid >> 6;
    int x = v;
#pragma unroll
    for (int d = 1; d < 64; d <<= 1) {
        int t = __shfl_up(x, d);
        if (lane >= d) x += t;
    }
    __shared__ int wt[4];
    if (lane == 63) wt[w] = x;
    __syncthreads();
    int base = 0;
#pragma unroll
    for (int i = 0; i < 3; ++i)
        if (i < w) base += wt[i];
    if (tid < nb) bbase[tid] = base + x - v;
}

__global__ __launch_bounds__(256) void scan_apply_kernel(int* __restrict__ off,
                                                         const int* __restrict__ bbase,
                                                         int n, int E) {
    const int gid = blockIdx.x * 256 + threadIdx.x;
    if (gid < n) off[gid] += bbase[blockIdx.x];
    if (gid == n) off[n] = E;
}

__global__ __launch_bounds__(256) void dinv_kernel(const int* __restrict__ cnt,
                                                   float* __restrict__ dinv, int n) {
    int i = blockIdx.x * 256 + threadIdx.x;
    if (i < n) {
        int c = cnt[i];
        dinv[i] = (c > 0) ? 1.0f / sqrtf((float)c) : 0.0f;
    }
}

__global__ __launch_bounds__(256) void scatter_kernel(const int* __restrict__ row,
                                                      const int* __restrict__ col,
                                                      const int* __restrict__ off,
                                                      const int* __restrict__ rank,
                                                      const float* __restrict__ dinv,
                                                      int2* __restrict__ recs, int E) {
    int e = blockIdx.x * 256 + threadIdx.x;
    if (e >= E) return;
    const int r = row[e], c = col[e];
    const int pos = off[c] + rank[e];
    recs[pos] = make_int2(r, __float_as_int(dinv[r] * dinv[c]));
}

// x (fp32 [N][16]) -> xcat cols 0..15 (fp16, row stride 64)
__global__ __launch_bounds__(256) void tohalf_kernel(const float* __restrict__ in,
                                                     __half* __restrict__ xcat, int N) {
    int i = blockIdx.x * 256 + threadIdx.x;
    if (i >= N * 2) return;
    const int n = i >> 1, q = i & 1;
    const float4 v0 = ((const float4*)in)[n * 4 + q * 2 + 0];
    const float4 v1 = ((const float4*)in)[n * 4 + q * 2 + 1];
    int4 o;
    o.x = f2i2(v0.x, v0.y);
    o.y = f2i2(v0.z, v0.w);
    o.z = f2i2(v1.x, v1.y);
    o.w = f2i2(v1.z, v1.w);
    ((int4*)xcat)[n * 8 + q] = o;
}

// ---------------- pure fp16 hop: out-slice = A_norm * in-slice ----------------
// DQ lanes/node, each owns one int4 (8 halfs). S4 = row stride in int4 units.
// in/out are pre-offset to the source/dest column slice of the cat buffer.

template <int DQ, int S4>
__global__ __launch_bounds__(256) void gatherh_kernel(const int* __restrict__ off,
                                                      const int2* __restrict__ recs,
                                                      const __half* __restrict__ hin,
                                                      __half* __restrict__ hout, int nNodes) {
    const int t = blockIdx.x * 256 + threadIdx.x;
    const int n = t / DQ;
    const int q = t & (DQ - 1);
    if (n >= nNodes) return;
    const int4* __restrict__ h4 = (const int4*)hin;
    F8 s = {};
    int e = off[n];
    const int e1 = off[n + 1];
    for (; e + 4 <= e1; e += 4) {
        const int2 r0 = recs[e + 0];
        const int2 r1 = recs[e + 1];
        const int2 r2 = recs[e + 2];
        const int2 r3 = recs[e + 3];
        const int4 g0 = h4[r0.x * S4 + q];
        const int4 g1 = h4[r1.x * S4 + q];
        const int4 g2 = h4[r2.x * S4 + q];
        const int4 g3 = h4[r3.x * S4 + q];
        fma8(s, g0, __int_as_float(r0.y));
        fma8(s, g1, __int_as_float(r1.y));
        fma8(s, g2, __int_as_float(r2.y));
        fma8(s, g3, __int_as_float(r3.y));
    }
    for (; e < e1; ++e) {
        const int2 r = recs[e];
        fma8(s, h4[r.x * S4 + q], __int_as_float(r.y));
    }
    int4 o;
    o.x = f2i2(s.a.x, s.a.y);
    o.y = f2i2(s.b.x, s.b.y);
    o.z = f2i2(s.c.x, s.c.y);
    o.w = f2i2(s.d.x, s.d.y);
    ((int4*)hout)[n * S4 + q] = o;
}

// ---------------- W pack: [K][64] fp32 -> MFMA B-fragment order fp16 ----------------
// Bp[t= (kk*4+nt)*64 + l] holds 8 halfs: j -> W[kk*32 + (l>>4)*8 + j][nt*16 + (l&15)]

__global__ __launch_bounds__(256) void packB_kernel(const float* __restrict__ W,
                                                    __half* __restrict__ Bp, int total) {
    const int t = blockIdx.x * 256 + threadIdx.x;
    if (t >= total) return;
    const int kk = t >> 8;
    const int nt = (t >> 6) & 3;
    const int l = t & 63;
    const int m = l & 15, kg = l >> 4;
    const int col = nt * 16 + m;
    __half tmp[8];
#pragma unroll
    for (int j = 0; j < 8; ++j) {
        const int k = kk * 32 + kg * 8 + j;
        tmp[j] = __float2half(W[k * 64 + col]);
    }
    ((int4*)Bp)[t] = *(int4*)tmp;
}

// ---------------- MFMA concat-GEMM: out = relu(A[N][K] @ W[K][64] + b) ----------------
// A row stride == K (cat buffer). Out: fp16 into cat buffer cols 0..63 (stride 256).
// Wave handles 32 nodes x 64 cols; block = 4 waves = 128 nodes.

template <int K>
__global__ __launch_bounds__(256) void gemmcat_mfma(const __half* __restrict__ A,
                                                    const __half* __restrict__ Bp,
                                                    const float* __restrict__ bias,
                                                    __half* __restrict__ out, int N) {
    const int wave = threadIdx.x >> 6;
    const int lane = threadIdx.x & 63;
    const int nb = blockIdx.x * 128 + wave * 32;
    const int m = lane & 15;
    const int kg = lane >> 4;

    const int row0 = min(nb + m, N - 1);
    const int row1 = min(nb + 16 + m, N - 1);
    const f16x8* a0p = (const f16x8*)(A + (size_t)row0 * K + kg * 8);
    const f16x8* a1p = (const f16x8*)(A + (size_t)row1 * K + kg * 8);
    const f16x8* bp = (const f16x8*)Bp + lane;

    f32x4 acc[2][4];
#pragma unroll
    for (int nt = 0; nt < 4; ++nt) {
        const float bv = bias[nt * 16 + m];
        acc[0][nt] = (f32x4){bv, bv, bv, bv};
        acc[1][nt] = (f32x4){bv, bv, bv, bv};
    }

#pragma unroll
    for (int kk = 0; kk < K / 32; ++kk) {
        const f16x8 a0 = a0p[kk * 4];
        const f16x8 a1 = a1p[kk * 4];
#pragma unroll
        for (int nt = 0; nt < 4; ++nt) {
            const f16x8 b = bp[(kk * 4 + nt) * 64];
            acc[0][nt] = __builtin_amdgcn_mfma_f32_16x16x32_f16(a0, b, acc[0][nt], 0, 0, 0);
            acc[1][nt] = __builtin_amdgcn_mfma_f32_16x16x32_f16(a1, b, acc[1][nt], 0, 0, 0);
        }
    }

#pragma unroll
    for (int mt = 0; mt < 2; ++mt) {
#pragma unroll
        for (int nt = 0; nt < 4; ++nt) {
#pragma unroll
            for (int r = 0; r < 4; ++r) {
                const int node = nb + mt * 16 + kg * 4 + r;
                if (node < N) {
                    const float v = fmaxf(acc[mt][nt][r], 0.f);
                    out[(size_t)node * 256 + nt * 16 + m] = __float2half(v);
                }
            }
        }
    }
}

// ---------------- layer 4: four 4-dim projections from fp16 h (stride 256) ----------------

__global__ __launch_bounds__(256) void proj4h_kernel(const __half* __restrict__ h,
                                                     const float* __restrict__ W,
                                                     float* __restrict__ P0,
                                                     float* __restrict__ P1,
                                                     float* __restrict__ P2,
                                                     float* __restrict__ P3, int nNodes) {
    __shared__ float Ws[4 * 64 * 4];
    for (int i = threadIdx.x; i < 1024; i += 256) Ws[i] = W[i];
    __syncthreads();
    const int k = threadIdx.x & 3;
    const int n = blockIdx.x * 64 + (threadIdx.x >> 2);
    if (n >= nNodes) return;
    const int4* __restrict__ h8 = (const int4*)h + (size_t)n * 32;  // row stride 256 halfs
    const float4* W4 = (const float4*)(Ws + k * 256);
    float4 acc = make_float4(0.f, 0.f, 0.f, 0.f);
#pragma unroll
    for (int i8 = 0; i8 < 8; ++i8) {
        const int4 g = h8[i8];
        const float2 f0 = i2f2(g.x), f1 = i2f2(g.y), f2v = i2f2(g.z), f3 = i2f2(g.w);
        const float hv[8] = {f0.x, f0.y, f1.x, f1.y, f2v.x, f2v.y, f3.x, f3.y};
#pragma unroll
        for (int j = 0; j < 8; ++j) {
            const float4 wr = W4[i8 * 8 + j];
            acc.x += hv[j] * wr.x;
            acc.y += hv[j] * wr.y;
            acc.z += hv[j] * wr.z;
            acc.w += hv[j] * wr.w;
        }
    }
    float4* dst = (k == 0) ? (float4*)P0 : (k == 1) ? (float4*)P1 : (k == 2) ? (float4*)P2
                                                                             : (float4*)P3;
    dst[n] = acc;
}

// Horner step on 4-dim fp32 signals: out[n] = P[n] (+bias) + sum_e norm_e * U[src_e]
template <bool FINAL>
__global__ __launch_bounds__(256) void prop1_add_kernel(const int* __restrict__ off,
                                                        const int2* __restrict__ recs,
                                                        const float* __restrict__ Uin,
                                                        const float* __restrict__ P,
                                                        const float* __restrict__ b,
                                                        float* __restrict__ out, int nNodes) {
    const int n = blockIdx.x * 256 + threadIdx.x;
    if (n >= nNodes) return;
    const float4* __restrict__ u4 = (const float4*)Uin;
    float4 acc = ((const float4*)P)[n];
    if (FINAL) {
        const float4 bv = *(const float4*)b;
        acc.x += bv.x;
        acc.y += bv.y;
        acc.z += bv.z;
        acc.w += bv.w;
    }
    int e = off[n];
    const int e1 = off[n + 1];
    for (; e + 4 <= e1; e += 4) {
        const int2 r0 = recs[e + 0];
        const int2 r1 = recs[e + 1];
        const int2 r2 = recs[e + 2];
        const int2 r3 = recs[e + 3];
        const float4 a = u4[r0.x], bb = u4[r1.x], c = u4[r2.x], d = u4[r3.x];
        const float w0 = __int_as_float(r0.y), w1 = __int_as_float(r1.y);
        const float w2 = __int_as_float(r2.y), w3 = __int_as_float(r3.y);
        acc.x += w0 * a.x + w1 * bb.x + w2 * c.x + w3 * d.x;
        acc.y += w0 * a.y + w1 * bb.y + w2 * c.y + w3 * d.y;
        acc.z += w0 * a.z + w1 * bb.z + w2 * c.z + w3 * d.z;
        acc.w += w0 * a.w + w1 * bb.w + w2 * c.w + w3 * d.w;
    }
    for (; e < e1; ++e) {
        const int2 r = recs[e];
        const float ww = __int_as_float(r.y);
        const float4 hv = u4[r.x];
        acc.x += ww * hv.x;
        acc.y += ww * hv.y;
        acc.z += ww * hv.z;
        acc.w += ww * hv.w;
    }
    ((float4*)out)[n] = acc;
}

// ---------------- host ----------------

extern "C" void kernel_launch(void* const* d_in, const int* in_sizes, int n_in,
                              void* d_out, int out_size, void* d_ws, size_t ws_size,
                              hipStream_t stream) {
    const float* x = (const float*)d_in[0];
    const int* ei = (const int*)d_in[1];
    const float* W[5] = {(const float*)d_in[2], (const float*)d_in[4], (const float*)d_in[6],
                         (const float*)d_in[8], (const float*)d_in[10]};
    const float* bb[5] = {(const float*)d_in[3], (const float*)d_in[5], (const float*)d_in[7],
                          (const float*)d_in[9], (const float*)d_in[11]};
    const int E = in_sizes[1] / 2;   // 800000
    const int N = in_sizes[0] / 16;  // 50000
    float* outp = (float*)d_out;

    char* p = (char*)d_ws;
    auto alloc = [&](size_t bytes) {
        char* r = p;
        p += (bytes + 255) & ~size_t(255);
        return r;
    };
    const int nb = (N + 255) / 256;
    int* cnt = (int*)alloc((size_t)N * 4);
    int* off = (int*)alloc((size_t)(N + 1) * 4);
    float* dinv = (float*)alloc((size_t)N * 4);
    int* bsum = (int*)alloc((size_t)nb * 4);
    int* bbase = (int*)alloc((size_t)nb * 4);
    int* rank = (int*)alloc((size_t)E * 4);
    int2* recs = (int2*)alloc((size_t)E * 8);
    __half* xcat = (__half*)alloc((size_t)N * 64 * 2);
    __half* hcatA = (__half*)alloc((size_t)N * 256 * 2);
    __half* hcatB = (__half*)alloc((size_t)N * 256 * 2);
    __half* Bp0 = (__half*)alloc((size_t)512 * 8 * 2);       // K=64 pack
    __half* Bp1 = (__half*)alloc((size_t)2048 * 8 * 2);      // K=256 packs
    __half* Bp2 = (__half*)alloc((size_t)2048 * 8 * 2);
    __half* Bp3 = (__half*)alloc((size_t)2048 * 8 * 2);
    float* P0 = (float*)alloc((size_t)N * 4 * 4);
    float* P1 = (float*)alloc((size_t)N * 4 * 4);
    float* P2 = (float*)alloc((size_t)N * 4 * 4);
    float* P3 = (float*)alloc((size_t)N * 4 * 4);
    float* Ua = (float*)alloc((size_t)N * 4 * 4);
    float* Ub = (float*)alloc((size_t)N * 4 * 4);

    hipMemsetAsync(cnt, 0, (size_t)N * 4, stream);
    const int eb = (E + 255) / 256;
    count_rank_kernel<<<eb, 256, 0, stream>>>(ei + E, cnt, rank, E);
    scan_block_kernel<<<nb, 256, 0, stream>>>(cnt, off, bsum, N);
    scan_bsum_kernel<<<1, 256, 0, stream>>>(bsum, bbase, nb);
    scan_apply_kernel<<<nb, 256, 0, stream>>>(off, bbase, N, E);
    dinv_kernel<<<nb, 256, 0, stream>>>(cnt, dinv, N);
    scatter_kernel<<<eb, 256, 0, stream>>>(ei, ei + E, off, rank, dinv, recs, E);
    tohalf_kernel<<<(N * 2 + 255) / 256, 256, 0, stream>>>(x, xcat, N);
    packB_kernel<<<2, 256, 0, stream>>>(W[0], Bp0, 512);
    packB_kernel<<<8, 256, 0, stream>>>(W[1], Bp1, 2048);
    packB_kernel<<<8, 256, 0, stream>>>(W[2], Bp2, 2048);
    packB_kernel<<<8, 256, 0, stream>>>(W[3], Bp3, 2048);

    const int gh2 = (N * 2 + 255) / 256;   // DQ=2 hop grid
    const int gh8 = (N * 8 + 255) / 256;   // DQ=8 hop grid
    const int gm = (N + 127) / 128;        // MFMA gemm grid (128 nodes/block)
    const int gq = (N + 63) / 64;
    const int p1 = (N + 255) / 256;

    // Layer 0: hops fill xcat col-slices; MFMA GEMM K=64 -> hcatA cols 0..63
    gatherh_kernel<2, 8><<<gh2, 256, 0, stream>>>(off, recs, xcat + 0, xcat + 16, N);
    gatherh_kernel<2, 8><<<gh2, 256, 0, stream>>>(off, recs, xcat + 16, xcat + 32, N);
    gatherh_kernel<2, 8><<<gh2, 256, 0, stream>>>(off, recs, xcat + 32, xcat + 48, N);
    gemmcat_mfma<64><<<gm, 256, 0, stream>>>(xcat, Bp0, bb[0], hcatA, N);

    // Layers 1-3: hops fill hcat col-slices; MFMA GEMM K=256 -> other hcat cols 0..63
    __half* cur = hcatA;
    __half* nxt = hcatB;
    const __half* Bps[4] = {nullptr, Bp1, Bp2, Bp3};
    for (int l = 1; l <= 3; ++l) {
        gatherh_kernel<8, 32><<<gh8, 256, 0, stream>>>(off, recs, cur + 0, cur + 64, N);
        gatherh_kernel<8, 32><<<gh8, 256, 0, stream>>>(off, recs, cur + 64, cur + 128, N);
        gatherh_kernel<8, 32><<<gh8, 256, 0, stream>>>(off, recs, cur + 128, cur + 192, N);
        gemmcat_mfma<256><<<gm, 256, 0, stream>>>(cur, Bps[l], bb[l], nxt, N);
        __half* t = cur;
        cur = nxt;
        nxt = t;
    }

    // Layer 4: P_k = cur@W4_k (one fp16 read of cur), Horner on 4-dim fp32 signals
    proj4h_kernel<<<gq, 256, 0, stream>>>(cur, W[4], P0, P1, P2, P3, N);
    prop1_add_kernel<false><<<p1, 256, 0, stream>>>(off, recs, P3, P2, nullptr, Ua, N);
    prop1_add_kernel<false><<<p1, 256, 0, stream>>>(off, recs, Ua, P1, nullptr, Ub, N);
    prop1_add_kernel<true><<<p1, 256, 0, stream>>>(off, recs, Ub, P0, bb[4], outp, N);
}

// Round 8
// 336.465 us; speedup vs baseline: 1.9172x; 1.0036x over previous
//
#include <hip/hip_runtime.h>
#include <hip/hip_fp16.h>

typedef _Float16 f16x8 __attribute__((ext_vector_type(8)));
typedef float f32x4 __attribute__((ext_vector_type(4)));

// ---------------- fp16 helpers ----------------
union H2I { int i; __half2 h; };
static __device__ inline float2 i2f2(int v) {
    H2I u; u.i = v; return __half22float2(u.h);
}
static __device__ inline int f2i2(float a, float b) {
    H2I u; u.h = __floats2half2_rn(a, b); return u.i;
}

struct F8 { float2 a, b, c, d; };
static __device__ inline void fma8(F8& s, int4 g, float w) {
    float2 t;
    t = i2f2(g.x); s.a.x += w * t.x; s.a.y += w * t.y;
    t = i2f2(g.y); s.b.x += w * t.x; s.b.y += w * t.y;
    t = i2f2(g.z); s.c.x += w * t.x; s.c.y += w * t.y;
    t = i2f2(g.w); s.d.x += w * t.x; s.d.y += w * t.y;
}

// ---------------- CSR build ----------------

__global__ __launch_bounds__(256) void count_rank_kernel(const int* __restrict__ col,
                                                         int* __restrict__ cnt,
                                                         unsigned short* __restrict__ rank,
                                                         int E) {
    int e = blockIdx.x * 256 + threadIdx.x;
    if (e < E) rank[e] = (unsigned short)atomicAdd(&cnt[col[e]], 1);
}

__global__ __launch_bounds__(256) void scan_block_kernel(const int* __restrict__ cnt,
                                                         int* __restrict__ off,
                                                         int* __restrict__ bsum, int n) {
    const int gid = blockIdx.x * 256 + threadIdx.x;
    const int v = (gid < n) ? cnt[gid] : 0;
    const int lane = threadIdx.x & 63, w = threadIdx.x >> 6;
    int x = v;
#pragma unroll
    for (int d = 1; d < 64; d <<= 1) {
        int t = __shfl_up(x, d);
        if (lane >= d) x += t;
    }
    __shared__ int wt[4];
    if (lane == 63) wt[w] = x;
    __syncthreads();
    int base = 0;
#pragma unroll
    for (int i = 0; i < 3; ++i)
        if (i < w) base += wt[i];
    const int incl = base + x;
    if (gid < n) off[gid] = incl - v;
    if (threadIdx.x == 255) bsum[blockIdx.x] = incl;
}

__global__ __launch_bounds__(256) void scan_bsum_kernel(const int* __restrict__ bsum,
                                                        int* __restrict__ bbase, int nb) {
    const int tid = threadIdx.x;
    const int v = (tid < nb) ? bsum[tid] : 0;
    const int lane = tid & 63, w = tid >> 6;
    int x = v;
#pragma unroll
    for (int d = 1; d < 64; d <<= 1) {
        int t = __shfl_up(x, d);
        if (lane >= d) x += t;
    }
    __shared__ int wt[4];
    if (lane == 63) wt[w] = x;
    __syncthreads();
    int base = 0;
#pragma unroll
    for (int i = 0; i < 3; ++i)
        if (i < w) base += wt[i];
    if (tid < nb) bbase[tid] = base + x - v;
}

__global__ __launch_bounds__(256) void scan_apply_kernel(int* __restrict__ off,
                                                         const int* __restrict__ bbase,
                                                         int n, int E) {
    const int gid = blockIdx.x * 256 + threadIdx.x;
    if (gid < n) off[gid] += bbase[blockIdx.x];
    if (gid == n) off[n] = E;
}

// Fused prep: dinv (N), x->xcat fp16 (2N), packB for 4 layers (512 + 3*2048).
__global__ __launch_bounds__(256) void prep_kernel(const int* __restrict__ cnt,
                                                   float* __restrict__ dinv,
                                                   const float* __restrict__ x,
                                                   __half* __restrict__ xcat,
                                                   const float* __restrict__ W0,
                                                   const float* __restrict__ W1,
                                                   const float* __restrict__ W2,
                                                   const float* __restrict__ W3,
                                                   __half* __restrict__ Bp0,
                                                   __half* __restrict__ Bp1,
                                                   __half* __restrict__ Bp2,
                                                   __half* __restrict__ Bp3, int N) {
    int t = blockIdx.x * 256 + threadIdx.x;
    if (t < N) {
        const int c = cnt[t];
        dinv[t] = (c > 0) ? 1.0f / sqrtf((float)c) : 0.0f;
        return;
    }
    t -= N;
    if (t < 2 * N) {
        const int n = t >> 1, q = t & 1;
        const float4 v0 = ((const float4*)x)[n * 4 + q * 2 + 0];
        const float4 v1 = ((const float4*)x)[n * 4 + q * 2 + 1];
        int4 o;
        o.x = f2i2(v0.x, v0.y);
        o.y = f2i2(v0.z, v0.w);
        o.z = f2i2(v1.x, v1.y);
        o.w = f2i2(v1.z, v1.w);
        ((int4*)xcat)[n * 8 + q] = o;
        return;
    }
    t -= 2 * N;
    const float* W;
    __half* Bp;
    if (t < 512) {
        W = W0; Bp = Bp0;
    } else if (t < 512 + 2048) {
        W = W1; Bp = Bp1; t -= 512;
    } else if (t < 512 + 2 * 2048) {
        W = W2; Bp = Bp2; t -= 512 + 2048;
    } else if (t < 512 + 3 * 2048) {
        W = W3; Bp = Bp3; t -= 512 + 2 * 2048;
    } else {
        return;
    }
    const int kk = t >> 8;
    const int nt = (t >> 6) & 3;
    const int l = t & 63;
    const int m = l & 15, kg = l >> 4;
    const int col = nt * 16 + m;
    __half tmp[8];
#pragma unroll
    for (int j = 0; j < 8; ++j) {
        const int k = kk * 32 + kg * 8 + j;
        tmp[j] = __float2half(W[k * 64 + col]);
    }
    ((int4*)Bp)[t] = *(int4*)tmp;
}

__global__ __launch_bounds__(256) void scatter_kernel(const int* __restrict__ row,
                                                      const int* __restrict__ col,
                                                      const int* __restrict__ off,
                                                      const unsigned short* __restrict__ rank,
                                                      const float* __restrict__ dinv,
                                                      int2* __restrict__ recs, int E) {
    int e = blockIdx.x * 256 + threadIdx.x;
    if (e >= E) return;
    const int r = row[e], c = col[e];
    const int pos = off[c] + (int)rank[e];
    recs[pos] = make_int2(r, __float_as_int(dinv[r] * dinv[c]));
}

// ---------------- pure fp16 hop: out-slice = A_norm * in-slice ----------------
// DQ lanes/node, each owns one int4 (8 halfs). S4 = row stride in int4 units.
// 8x unrolled edge loop for deep MLP (latency-bound regime).

template <int DQ, int S4>
__global__ __launch_bounds__(256) void gatherh_kernel(const int* __restrict__ off,
                                                      const int2* __restrict__ recs,
                                                      const __half* __restrict__ hin,
                                                      __half* __restrict__ hout, int nNodes) {
    const int t = blockIdx.x * 256 + threadIdx.x;
    const int n = t / DQ;
    const int q = t & (DQ - 1);
    if (n >= nNodes) return;
    const int4* __restrict__ h4 = (const int4*)hin;
    F8 s = {};
    int e = off[n];
    const int e1 = off[n + 1];
    for (; e + 8 <= e1; e += 8) {
        const int2 r0 = recs[e + 0];
        const int2 r1 = recs[e + 1];
        const int2 r2 = recs[e + 2];
        const int2 r3 = recs[e + 3];
        const int2 r4 = recs[e + 4];
        const int2 r5 = recs[e + 5];
        const int2 r6 = recs[e + 6];
        const int2 r7 = recs[e + 7];
        const int4 g0 = h4[r0.x * S4 + q];
        const int4 g1 = h4[r1.x * S4 + q];
        const int4 g2 = h4[r2.x * S4 + q];
        const int4 g3 = h4[r3.x * S4 + q];
        const int4 g4 = h4[r4.x * S4 + q];
        const int4 g5 = h4[r5.x * S4 + q];
        const int4 g6 = h4[r6.x * S4 + q];
        const int4 g7 = h4[r7.x * S4 + q];
        fma8(s, g0, __int_as_float(r0.y));
        fma8(s, g1, __int_as_float(r1.y));
        fma8(s, g2, __int_as_float(r2.y));
        fma8(s, g3, __int_as_float(r3.y));
        fma8(s, g4, __int_as_float(r4.y));
        fma8(s, g5, __int_as_float(r5.y));
        fma8(s, g6, __int_as_float(r6.y));
        fma8(s, g7, __int_as_float(r7.y));
    }
    for (; e + 4 <= e1; e += 4) {
        const int2 r0 = recs[e + 0];
        const int2 r1 = recs[e + 1];
        const int2 r2 = recs[e + 2];
        const int2 r3 = recs[e + 3];
        const int4 g0 = h4[r0.x * S4 + q];
        const int4 g1 = h4[r1.x * S4 + q];
        const int4 g2 = h4[r2.x * S4 + q];
        const int4 g3 = h4[r3.x * S4 + q];
        fma8(s, g0, __int_as_float(r0.y));
        fma8(s, g1, __int_as_float(r1.y));
        fma8(s, g2, __int_as_float(r2.y));
        fma8(s, g3, __int_as_float(r3.y));
    }
    for (; e < e1; ++e) {
        const int2 r = recs[e];
        fma8(s, h4[r.x * S4 + q], __int_as_float(r.y));
    }
    int4 o;
    o.x = f2i2(s.a.x, s.a.y);
    o.y = f2i2(s.b.x, s.b.y);
    o.z = f2i2(s.c.x, s.c.y);
    o.w = f2i2(s.d.x, s.d.y);
    ((int4*)hout)[n * S4 + q] = o;
}

// ---------------- MFMA concat-GEMM: out = relu(A[N][K] @ W[K][64] + b) ----------------
// A row stride == K (cat buffer). Out: fp16 into cat buffer cols 0..63 (stride 256).
// Wave: 32 nodes x 64 cols; block = 4 waves = 128 nodes. Epilogue via LDS transpose
// so global writes are 64B-coalesced per thread.

template <int K>
__global__ __launch_bounds__(256) void gemmcat_mfma(const __half* __restrict__ A,
                                                    const __half* __restrict__ Bp,
                                                    const float* __restrict__ bias,
                                                    __half* __restrict__ out, int N) {
    __shared__ __half hs[128][72];  // 144B row stride: 16B-aligned, bank-spread
    const int wave = threadIdx.x >> 6;
    const int lane = threadIdx.x & 63;
    const int nb = blockIdx.x * 128 + wave * 32;
    const int m = lane & 15;
    const int kg = lane >> 4;

    const int row0 = min(nb + m, N - 1);
    const int row1 = min(nb + 16 + m, N - 1);
    const f16x8* a0p = (const f16x8*)(A + (size_t)row0 * K + kg * 8);
    const f16x8* a1p = (const f16x8*)(A + (size_t)row1 * K + kg * 8);
    const f16x8* bp = (const f16x8*)Bp + lane;

    f32x4 acc[2][4];
#pragma unroll
    for (int nt = 0; nt < 4; ++nt) {
        const float bv = bias[nt * 16 + m];
        acc[0][nt] = (f32x4){bv, bv, bv, bv};
        acc[1][nt] = (f32x4){bv, bv, bv, bv};
    }

#pragma unroll
    for (int kk = 0; kk < K / 32; ++kk) {
        const f16x8 a0 = a0p[kk * 4];
        const f16x8 a1 = a1p[kk * 4];
#pragma unroll
        for (int nt = 0; nt < 4; ++nt) {
            const f16x8 b = bp[(kk * 4 + nt) * 64];
            acc[0][nt] = __builtin_amdgcn_mfma_f32_16x16x32_f16(a0, b, acc[0][nt], 0, 0, 0);
            acc[1][nt] = __builtin_amdgcn_mfma_f32_16x16x32_f16(a1, b, acc[1][nt], 0, 0, 0);
        }
    }

    // stage C to LDS (relu here), then coalesced global write
#pragma unroll
    for (int mt = 0; mt < 2; ++mt) {
#pragma unroll
        for (int nt = 0; nt < 4; ++nt) {
#pragma unroll
            for (int r = 0; r < 4; ++r) {
                const int nl = wave * 32 + mt * 16 + kg * 4 + r;
                hs[nl][nt * 16 + m] = __float2half(fmaxf(acc[mt][nt][r], 0.f));
            }
        }
    }
    __syncthreads();
    const int nl = threadIdx.x >> 1;          // 0..127
    const int seg = threadIdx.x & 1;          // half-row
    const int node = blockIdx.x * 128 + nl;
    if (node >= N) return;
    const int4* src = (const int4*)&hs[nl][seg * 32];
    int4* dst = (int4*)(out + (size_t)node * 256 + seg * 32);
    dst[0] = src[0];
    dst[1] = src[1];
    dst[2] = src[2];
    dst[3] = src[3];
}

// ---------------- layer 4: four 4-dim projections from fp16 h (stride 256) ----------------

__global__ __launch_bounds__(256) void proj4h_kernel(const __half* __restrict__ h,
                                                     const float* __restrict__ W,
                                                     float* __restrict__ P0,
                                                     float* __restrict__ P1,
                                                     float* __restrict__ P2,
                                                     float* __restrict__ P3, int nNodes) {
    __shared__ float Ws[4 * 64 * 4];
    for (int i = threadIdx.x; i < 1024; i += 256) Ws[i] = W[i];
    __syncthreads();
    const int k = threadIdx.x & 3;
    const int n = blockIdx.x * 64 + (threadIdx.x >> 2);
    if (n >= nNodes) return;
    const int4* __restrict__ h8 = (const int4*)h + (size_t)n * 32;
    const float4* W4 = (const float4*)(Ws + k * 256);
    float4 acc = make_float4(0.f, 0.f, 0.f, 0.f);
#pragma unroll
    for (int i8 = 0; i8 < 8; ++i8) {
        const int4 g = h8[i8];
        const float2 f0 = i2f2(g.x), f1 = i2f2(g.y), f2v = i2f2(g.z), f3 = i2f2(g.w);
        const float hv[8] = {f0.x, f0.y, f1.x, f1.y, f2v.x, f2v.y, f3.x, f3.y};
#pragma unroll
        for (int j = 0; j < 8; ++j) {
            const float4 wr = W4[i8 * 8 + j];
            acc.x += hv[j] * wr.x;
            acc.y += hv[j] * wr.y;
            acc.z += hv[j] * wr.z;
            acc.w += hv[j] * wr.w;
        }
    }
    float4* dst = (k == 0) ? (float4*)P0 : (k == 1) ? (float4*)P1 : (k == 2) ? (float4*)P2
                                                                             : (float4*)P3;
    dst[n] = acc;
}

// Horner step on 4-dim fp32 signals: out[n] = P[n] (+bias) + sum_e norm_e * U[src_e]
template <bool FINAL>
__global__ __launch_bounds__(256) void prop1_add_kernel(const int* __restrict__ off,
                                                        const int2* __restrict__ recs,
                                                        const float* __restrict__ Uin,
                                                        const float* __restrict__ P,
                                                        const float* __restrict__ b,
                                                        float* __restrict__ out, int nNodes) {
    const int n = blockIdx.x * 256 + threadIdx.x;
    if (n >= nNodes) return;
    const float4* __restrict__ u4 = (const float4*)Uin;
    float4 acc = ((const float4*)P)[n];
    if (FINAL) {
        const float4 bv = *(const float4*)b;
        acc.x += bv.x;
        acc.y += bv.y;
        acc.z += bv.z;
        acc.w += bv.w;
    }
    int e = off[n];
    const int e1 = off[n + 1];
    for (; e + 4 <= e1; e += 4) {
        const int2 r0 = recs[e + 0];
        const int2 r1 = recs[e + 1];
        const int2 r2 = recs[e + 2];
        const int2 r3 = recs[e + 3];
        const float4 a = u4[r0.x], bb = u4[r1.x], c = u4[r2.x], d = u4[r3.x];
        const float w0 = __int_as_float(r0.y), w1 = __int_as_float(r1.y);
        const float w2 = __int_as_float(r2.y), w3 = __int_as_float(r3.y);
        acc.x += w0 * a.x + w1 * bb.x + w2 * c.x + w3 * d.x;
        acc.y += w0 * a.y + w1 * bb.y + w2 * c.y + w3 * d.y;
        acc.z += w0 * a.z + w1 * bb.z + w2 * c.z + w3 * d.z;
        acc.w += w0 * a.w + w1 * bb.w + w2 * c.w + w3 * d.w;
    }
    for (; e < e1; ++e) {
        const int2 r = recs[e];
        const float ww = __int_as_float(r.y);
        const float4 hv = u4[r.x];
        acc.x += ww * hv.x;
        acc.y += ww * hv.y;
        acc.z += ww * hv.z;
        acc.w += ww * hv.w;
    }
    ((float4*)out)[n] = acc;
}

// ---------------- host ----------------

extern "C" void kernel_launch(void* const* d_in, const int* in_sizes, int n_in,
                              void* d_out, int out_size, void* d_ws, size_t ws_size,
                              hipStream_t stream) {
    const float* x = (const float*)d_in[0];
    const int* ei = (const int*)d_in[1];
    const float* W[5] = {(const float*)d_in[2], (const float*)d_in[4], (const float*)d_in[6],
                         (const float*)d_in[8], (const float*)d_in[10]};
    const float* bb[5] = {(const float*)d_in[3], (const float*)d_in[5], (const float*)d_in[7],
                          (const float*)d_in[9], (const float*)d_in[11]};
    const int E = in_sizes[1] / 2;   // 800000
    const int N = in_sizes[0] / 16;  // 50000
    float* outp = (float*)d_out;

    char* p = (char*)d_ws;
    auto alloc = [&](size_t bytes) {
        char* r = p;
        p += (bytes + 255) & ~size_t(255);
        return r;
    };
    const int nb = (N + 255) / 256;
    int* cnt = (int*)alloc((size_t)N * 4);
    int* off = (int*)alloc((size_t)(N + 1) * 4);
    float* dinv = (float*)alloc((size_t)N * 4);
    int* bsum = (int*)alloc((size_t)nb * 4);
    int* bbase = (int*)alloc((size_t)nb * 4);
    unsigned short* rank = (unsigned short*)alloc((size_t)E * 2);
    int2* recs = (int2*)alloc((size_t)E * 8);
    __half* xcat = (__half*)alloc((size_t)N * 64 * 2);
    __half* hcatA = (__half*)alloc((size_t)N * 256 * 2);
    __half* hcatB = (__half*)alloc((size_t)N * 256 * 2);
    __half* Bp0 = (__half*)alloc((size_t)512 * 8 * 2);
    __half* Bp1 = (__half*)alloc((size_t)2048 * 8 * 2);
    __half* Bp2 = (__half*)alloc((size_t)2048 * 8 * 2);
    __half* Bp3 = (__half*)alloc((size_t)2048 * 8 * 2);
    float* P0 = (float*)alloc((size_t)N * 4 * 4);
    float* P1 = (float*)alloc((size_t)N * 4 * 4);
    float* P2 = (float*)alloc((size_t)N * 4 * 4);
    float* P3 = (float*)alloc((size_t)N * 4 * 4);
    float* Ua = (float*)alloc((size_t)N * 4 * 4);
    float* Ub = (float*)alloc((size_t)N * 4 * 4);

    hipMemsetAsync(cnt, 0, (size_t)N * 4, stream);
    const int eb = (E + 255) / 256;
    count_rank_kernel<<<eb, 256, 0, stream>>>(ei + E, cnt, rank, E);
    scan_block_kernel<<<nb, 256, 0, stream>>>(cnt, off, bsum, N);
    scan_bsum_kernel<<<1, 256, 0, stream>>>(bsum, bbase, nb);
    scan_apply_kernel<<<nb, 256, 0, stream>>>(off, bbase, N, E);
    const int prep_total = 3 * N + 512 + 3 * 2048;
    prep_kernel<<<(prep_total + 255) / 256, 256, 0, stream>>>(
        cnt, dinv, x, xcat, W[0], W[1], W[2], W[3], Bp0, Bp1, Bp2, Bp3, N);
    scatter_kernel<<<eb, 256, 0, stream>>>(ei, ei + E, off, rank, dinv, recs, E);

    const int gh2 = (N * 2 + 255) / 256;   // DQ=2 hop grid
    const int gh8 = (N * 8 + 255) / 256;   // DQ=8 hop grid
    const int gm = (N + 127) / 128;        // MFMA gemm grid (128 nodes/block)
    const int gq = (N + 63) / 64;
    const int p1 = (N + 255) / 256;

    // Layer 0: hops fill xcat col-slices; MFMA GEMM K=64 -> hcatA cols 0..63
    gatherh_kernel<2, 8><<<gh2, 256, 0, stream>>>(off, recs, xcat + 0, xcat + 16, N);
    gatherh_kernel<2, 8><<<gh2, 256, 0, stream>>>(off, recs, xcat + 16, xcat + 32, N);
    gatherh_kernel<2, 8><<<gh2, 256, 0, stream>>>(off, recs, xcat + 32, xcat + 48, N);
    gemmcat_mfma<64><<<gm, 256, 0, stream>>>(xcat, Bp0, bb[0], hcatA, N);

    // Layers 1-3: hops fill hcat col-slices; MFMA GEMM K=256 -> other hcat cols 0..63
    __half* cur = hcatA;
    __half* nxt = hcatB;
    const __half* Bps[4] = {nullptr, Bp1, Bp2, Bp3};
    for (int l = 1; l <= 3; ++l) {
        gatherh_kernel<8, 32><<<gh8, 256, 0, stream>>>(off, recs, cur + 0, cur + 64, N);
        gatherh_kernel<8, 32><<<gh8, 256, 0, stream>>>(off, recs, cur + 64, cur + 128, N);
        gatherh_kernel<8, 32><<<gh8, 256, 0, stream>>>(off, recs, cur + 128, cur + 192, N);
        gemmcat_mfma<256><<<gm, 256, 0, stream>>>(cur, Bps[l], bb[l], nxt, N);
        __half* t = cur;
        cur = nxt;
        nxt = t;
    }

    // Layer 4: P_k = cur@W4_k (one fp16 read of cur), Horner on 4-dim fp32 signals
    proj4h_kernel<<<gq, 256, 0, stream>>>(cur, W[4], P0, P1, P2, P3, N);
    prop1_add_kernel<false><<<p1, 256, 0, stream>>>(off, recs, P3, P2, nullptr, Ua, N);
    prop1_add_kernel<false><<<p1, 256, 0, stream>>>(off, recs, Ua, P1, nullptr, Ub, N);
    prop1_add_kernel<true><<<p1, 256, 0, stream>>>(off, recs, Ub, P0, bb[4], outp, N);
}